// Round 1
// baseline (1417.917 us; speedup 1.0000x reference)
//
#include <hip/hip_runtime.h>
#include <math.h>

// Problem constants
#define TT 48
#define EE 32
#define CC 64      // C0 == C1 == 64
#define NSEQ (16*2048)
#define HH1 256
#define HH2 128
#define NP 12

// ws layout (floats):
//   [0)      Wcc  96*64  (folded W_in @ W_conv, im2col layout [kidx][c])
//   [6144)   btot 64     (bc0+bc1+bc2+b_conv)
//   [6208)   bc0  64
//   [6272)   bc2  64
//   [6336)   ctx  32768*64
#define WS_WCC  0
#define WS_BTOT 6144
#define WS_BC0  6208
#define WS_BC2  6272
#define WS_CTX  6336

// ---------------------------------------------------------------------------
// Prep: fold W_in into conv weights.  Wcc[(dt*32+e)*64+c] = sum_c0 W_in[e][c0]*W_conv[dt][c0][c]
// bc[dt][c] = sum_c0 b_in[c0]*W_conv[dt][c0][c];  btot = bc0+bc1+bc2+b_conv
// ---------------------------------------------------------------------------
__global__ __launch_bounds__(256) void prep_kernel(
    const float* __restrict__ W_in, const float* __restrict__ b_in,
    const float* __restrict__ W_conv, const float* __restrict__ b_conv,
    float* __restrict__ ws)
{
  int tid = threadIdx.x;
  if (blockIdx.x < 24) {
    int gid = blockIdx.x * 256 + tid;   // 0..6143
    int kk = gid >> 6;                  // 0..95
    int c  = gid & 63;
    int dt = kk >> 5;
    int e  = kk & 31;
    const float* wrow = W_in + e * 64;
    const float* wc   = W_conv + dt * 4096 + c;
    float acc = 0.f;
    #pragma unroll 8
    for (int c0 = 0; c0 < 64; ++c0)
      acc = fmaf(wrow[c0], wc[c0 * 64], acc);
    ws[WS_WCC + kk * 64 + c] = acc;
  } else if (tid < 64) {
    int c = tid;
    float s[3];
    for (int dt = 0; dt < 3; ++dt) {
      const float* wc = W_conv + dt * 4096 + c;
      float a = 0.f;
      for (int c0 = 0; c0 < 64; ++c0) a = fmaf(b_in[c0], wc[c0 * 64], a);
      s[dt] = a;
    }
    ws[WS_BC0 + c]  = s[0];
    ws[WS_BC2 + c]  = s[2];
    ws[WS_BTOT + c] = s[0] + s[1] + s[2] + b_conv[c];
  }
}

// ---------------------------------------------------------------------------
// Attention kernel: one block per sequence. Fused conv -> relu -> k,v (all t),
// q (t=47 only) -> scores -> softmax -> ctx_last.  LDS ~43.7KB -> 3 blocks/CU.
// Thread tile: 4 channels x 3 timesteps per thread (12 FMA per weight float4).
// ---------------------------------------------------------------------------
__global__ __launch_bounds__(256) void attn_kernel(
    const float* __restrict__ x,
    const float* __restrict__ Wq, const float* __restrict__ bq,
    const float* __restrict__ Wk, const float* __restrict__ bk,
    const float* __restrict__ Wv, const float* __restrict__ bv,
    const float* __restrict__ ws, float* __restrict__ ctx)
{
  __shared__ __align__(16) float xs[50 * 32];   // padded x: row0 / row49 are zeros
  __shared__ float h1[48 * 64];
  __shared__ float kb[48 * 64];
  __shared__ float vb[48 * 64];
  __shared__ float qv[64];
  __shared__ float sc[48];

  const int tid = threadIdx.x;
  const int seq = blockIdx.x;
  const float* __restrict__ Wcc = ws + WS_WCC;

  // zero pad rows
  if (tid < 32)       xs[tid] = 0.f;
  else if (tid < 64)  xs[49 * 32 + (tid - 32)] = 0.f;

  // load x sequence (1536 floats = 384 float4)
  const float4* xg = reinterpret_cast<const float4*>(x + (size_t)seq * (TT * EE));
  float4* xl = reinterpret_cast<float4*>(xs + 32);
  xl[tid] = xg[tid];
  if (tid < 128) xl[256 + tid] = xg[256 + tid];
  __syncthreads();

  const int lane16 = tid & 15;
  const int tgrp   = tid >> 4;       // 0..15
  const int c4     = lane16 * 4;     // channel tile
  const int t0     = tgrp * 3;       // timestep tile

  // ---- conv (as GEMM on im2col of x): M=48 N=64 K=96 ----
  float acc[3][4] = {};
  #pragma unroll 4
  for (int kk = 0; kk < 96; ++kk) {
    float4 w = *reinterpret_cast<const float4*>(Wcc + kk * 64 + c4);
    #pragma unroll
    for (int j = 0; j < 3; ++j) {
      float xv = xs[(t0 + j) * 32 + kk];   // im2col row t starts at xs[t*32]
      acc[j][0] = fmaf(xv, w.x, acc[j][0]);
      acc[j][1] = fmaf(xv, w.y, acc[j][1]);
      acc[j][2] = fmaf(xv, w.z, acc[j][2]);
      acc[j][3] = fmaf(xv, w.w, acc[j][3]);
    }
  }
  {
    const float* btot = ws + WS_BTOT;
    const float* bc0  = ws + WS_BC0;
    const float* bc2  = ws + WS_BC2;
    #pragma unroll
    for (int j = 0; j < 3; ++j) {
      int t = t0 + j;
      #pragma unroll
      for (int i = 0; i < 4; ++i) {
        int c = c4 + i;
        float b = btot[c];
        if (t == 0)  b -= bc0[c];   // pad row contributes no b_in term
        if (t == 47) b -= bc2[c];
        h1[t * 64 + c] = fmaxf(acc[j][i] + b, 0.f);
      }
    }
  }
  __syncthreads();

  // ---- k and v projections: M=48 N=64 K=64 (shared h1 reads) ----
  float ak[3][4] = {}, av[3][4] = {};
  #pragma unroll 2
  for (int k = 0; k < 64; ++k) {
    float4 wk = *reinterpret_cast<const float4*>(Wk + k * 64 + c4);
    float4 wv = *reinterpret_cast<const float4*>(Wv + k * 64 + c4);
    #pragma unroll
    for (int j = 0; j < 3; ++j) {
      float h = h1[(t0 + j) * 64 + k];
      ak[j][0] = fmaf(h, wk.x, ak[j][0]);
      ak[j][1] = fmaf(h, wk.y, ak[j][1]);
      ak[j][2] = fmaf(h, wk.z, ak[j][2]);
      ak[j][3] = fmaf(h, wk.w, ak[j][3]);
      av[j][0] = fmaf(h, wv.x, av[j][0]);
      av[j][1] = fmaf(h, wv.y, av[j][1]);
      av[j][2] = fmaf(h, wv.z, av[j][2]);
      av[j][3] = fmaf(h, wv.w, av[j][3]);
    }
  }
  #pragma unroll
  for (int j = 0; j < 3; ++j) {
    int t = t0 + j;
    #pragma unroll
    for (int i = 0; i < 4; ++i) {
      int c = c4 + i;
      kb[t * 64 + c] = ak[j][i] + bk[c];
      vb[t * 64 + c] = av[j][i] + bv[c];
    }
  }
  __syncthreads();

  // ---- q at t=47 only ----
  if (tid < 64) {
    int c = tid;
    float a = bq[c];
    #pragma unroll 4
    for (int k = 0; k < 64; ++k)
      a = fmaf(h1[47 * 64 + k], Wq[k * 64 + c], a);
    qv[c] = a;
  }
  __syncthreads();

  // ---- scores (last row only) ----
  if (tid < 48) {
    int s = tid;
    float a = 0.f;
    #pragma unroll 4
    for (int c = 0; c < 64; ++c)
      a = fmaf(qv[c], kb[s * 64 + c], a);
    sc[s] = a * 0.125f;   // / sqrt(64)
  }
  __syncthreads();

  // ---- softmax over 48, single wave ----
  if (tid < 64) {
    float v = (tid < 48) ? sc[tid] : -INFINITY;
    float mx = v;
    #pragma unroll
    for (int m = 32; m > 0; m >>= 1) mx = fmaxf(mx, __shfl_xor(mx, m, 64));
    float p = __expf(v - mx);
    float sum = p;
    #pragma unroll
    for (int m = 32; m > 0; m >>= 1) sum += __shfl_xor(sum, m, 64);
    if (tid < 48) sc[tid] = p / sum;
  }
  __syncthreads();

  // ---- ctx_last = attn . v ----
  if (tid < 64) {
    int c = tid;
    float a = 0.f;
    #pragma unroll 4
    for (int s = 0; s < 48; ++s)
      a = fmaf(sc[s], vb[s * 64 + c], a);
    ctx[(size_t)seq * 64 + c] = a;
  }
}

// ---------------------------------------------------------------------------
// MLP kernel: 32 rows/block (1024 blocks), weights amortized 32x, tiled GEMM.
// Writes the (B, NPRED, N) transpose directly.
// ---------------------------------------------------------------------------
__global__ __launch_bounds__(256) void mlp_kernel(
    const float* __restrict__ ctx,
    const float* __restrict__ W1, const float* __restrict__ b1,
    const float* __restrict__ W2, const float* __restrict__ b2,
    const float* __restrict__ W3, const float* __restrict__ b3,
    float* __restrict__ out)
{
  __shared__ __align__(16) float Xs[32 * 64];
  __shared__ float z1[32 * 256];
  __shared__ float z2[32 * 128];
  const int tid = threadIdx.x;
  const int r0  = blockIdx.x * 32;

  // load 32 rows of ctx (2048 floats = 512 float4)
  const float4* xg = reinterpret_cast<const float4*>(ctx + (size_t)r0 * 64);
  float4* xl = reinterpret_cast<float4*>(Xs);
  xl[tid]       = xg[tid];
  xl[256 + tid] = xg[256 + tid];
  __syncthreads();

  // layer 1: 32x256, K=64. thread tile 4 rows x 8 cols.
  {
    const int cg = tid & 31, rg = tid >> 5;
    const int c8 = cg * 8, r4 = rg * 4;
    float a[4][8] = {};
    #pragma unroll 2
    for (int k = 0; k < 64; ++k) {
      float4 wA = *reinterpret_cast<const float4*>(W1 + k * 256 + c8);
      float4 wB = *reinterpret_cast<const float4*>(W1 + k * 256 + c8 + 4);
      #pragma unroll
      for (int j = 0; j < 4; ++j) {
        float xv = Xs[(r4 + j) * 64 + k];
        a[j][0] = fmaf(xv, wA.x, a[j][0]);
        a[j][1] = fmaf(xv, wA.y, a[j][1]);
        a[j][2] = fmaf(xv, wA.z, a[j][2]);
        a[j][3] = fmaf(xv, wA.w, a[j][3]);
        a[j][4] = fmaf(xv, wB.x, a[j][4]);
        a[j][5] = fmaf(xv, wB.y, a[j][5]);
        a[j][6] = fmaf(xv, wB.z, a[j][6]);
        a[j][7] = fmaf(xv, wB.w, a[j][7]);
      }
    }
    #pragma unroll
    for (int j = 0; j < 4; ++j)
      #pragma unroll
      for (int i = 0; i < 8; ++i)
        z1[(r4 + j) * 256 + c8 + i] = fmaxf(a[j][i] + b1[c8 + i], 0.f);
  }
  __syncthreads();

  // layer 2: 32x128, K=256. thread tile 4 rows x 4 cols.
  {
    const int cg = tid & 31, rg = tid >> 5;
    const int c4 = cg * 4, r4 = rg * 4;
    float a[4][4] = {};
    #pragma unroll 2
    for (int k = 0; k < 256; ++k) {
      float4 w = *reinterpret_cast<const float4*>(W2 + k * 128 + c4);
      #pragma unroll
      for (int j = 0; j < 4; ++j) {
        float zv = z1[(r4 + j) * 256 + k];
        a[j][0] = fmaf(zv, w.x, a[j][0]);
        a[j][1] = fmaf(zv, w.y, a[j][1]);
        a[j][2] = fmaf(zv, w.z, a[j][2]);
        a[j][3] = fmaf(zv, w.w, a[j][3]);
      }
    }
    #pragma unroll
    for (int j = 0; j < 4; ++j)
      #pragma unroll
      for (int i = 0; i < 4; ++i)
        z2[(r4 + j) * 128 + c4 + i] = fmaxf(a[j][i] + b2[c4 + i], 0.f);
  }
  __syncthreads();

  // layer 3 (32x12, K=128) + transposed store: out[b*12*2048 + p*2048 + n]
  for (int o = tid; o < 32 * NP; o += 256) {
    int r = o / NP, p = o - r * NP;
    float a = b3[p];
    const float* zr = z2 + r * 128;
    #pragma unroll 4
    for (int k = 0; k < 128; ++k)
      a = fmaf(zr[k], W3[k * NP + p], a);
    int row = r0 + r;
    int bb = row >> 11, nn = row & 2047;
    out[(size_t)bb * (NP * 2048) + p * 2048 + nn] = a;
  }
}

// ---------------------------------------------------------------------------
extern "C" void kernel_launch(void* const* d_in, const int* in_sizes, int n_in,
                              void* d_out, int out_size, void* d_ws, size_t ws_size,
                              hipStream_t stream) {
  const float* x      = (const float*)d_in[0];
  const float* W_in   = (const float*)d_in[1];
  const float* b_in   = (const float*)d_in[2];
  const float* W_conv = (const float*)d_in[3];
  const float* b_conv = (const float*)d_in[4];
  const float* Wq     = (const float*)d_in[5];
  const float* bq     = (const float*)d_in[6];
  const float* Wk     = (const float*)d_in[7];
  const float* bk     = (const float*)d_in[8];
  const float* Wv     = (const float*)d_in[9];
  const float* bv     = (const float*)d_in[10];
  const float* W1     = (const float*)d_in[11];
  const float* b1     = (const float*)d_in[12];
  const float* W2     = (const float*)d_in[13];
  const float* b2     = (const float*)d_in[14];
  const float* W3     = (const float*)d_in[15];
  const float* b3     = (const float*)d_in[16];
  float* ws  = (float*)d_ws;
  float* out = (float*)d_out;

  prep_kernel<<<25, 256, 0, stream>>>(W_in, b_in, W_conv, b_conv, ws);
  attn_kernel<<<NSEQ, 256, 0, stream>>>(x, Wq, bq, Wk, bk, Wv, bv, ws, ws + WS_CTX);
  mlp_kernel<<<NSEQ / 32, 256, 0, stream>>>(ws + WS_CTX, W1, b1, W2, b2, W3, b3, out);
}

// Round 2
// 728.162 us; speedup vs baseline: 1.9473x; 1.9473x over previous
//
#include <hip/hip_runtime.h>
#include <math.h>

// Problem constants
#define TT 48
#define EE 32
#define CC 64      // C0 == C1 == 64
#define NSEQ (16*2048)
#define HH1 256
#define HH2 128
#define NP 12

// MFMA fragment types (gfx950: mfma_f32_16x16x32_bf16)
typedef __bf16 bf16x8 __attribute__((ext_vector_type(8)));
typedef float  f32x4  __attribute__((ext_vector_type(4)));

// ws layout:
//   bf16 region (viewed as __bf16*):
//     [0)      WccB   96*64 bf16, B-frag swizzled: [((k>>3)*64+n)*8 + (k&7)]
//     [6144)   WkB    64*64 bf16, same swizzle
//     [10240)  WvB    64*64 bf16, same swizzle
//   float region (viewed as float*):
//     [7168)   btot 64   (bc0+bc1+bc2+b_conv)
//     [7232)   bc0  64
//     [7296)   bc2  64
//     [7360)   ctx  32768*64
#define WS_BTOT 7168
#define WS_BC0  7232
#define WS_BC2  7296
#define WS_CTX  7360

__device__ __forceinline__ f32x4 zero4() {
  f32x4 z; z[0] = 0.f; z[1] = 0.f; z[2] = 0.f; z[3] = 0.f; return z;
}

// ---------------------------------------------------------------------------
// Prep: fold W_in into conv weights, convert all GEMM weights to bf16 in
// B-fragment-swizzled order so attn waves load B-frags as single 16B loads.
// Wcc[k][c] = sum_c0 W_in[e][c0]*W_conv[dt][c0][c],  k = dt*32+e
// bc[dt][c] = sum_c0 b_in[c0]*W_conv[dt][c0][c];  btot = bc0+bc1+bc2+b_conv
// ---------------------------------------------------------------------------
__global__ __launch_bounds__(256) void prep_kernel(
    const float* __restrict__ W_in, const float* __restrict__ b_in,
    const float* __restrict__ W_conv, const float* __restrict__ b_conv,
    const float* __restrict__ Wk, const float* __restrict__ Wv,
    float* __restrict__ ws)
{
  __bf16* wsb = (__bf16*)ws;
  const int tid = threadIdx.x;
  const int bid = blockIdx.x;
  if (bid < 24) {
    int gid = bid * 256 + tid;          // 0..6143
    int kk = gid >> 6;                  // 0..95
    int c  = gid & 63;
    int dt = kk >> 5;
    int e  = kk & 31;
    const float* wrow = W_in + e * 64;
    const float* wc   = W_conv + dt * 4096 + c;
    float acc = 0.f;
    #pragma unroll 8
    for (int c0 = 0; c0 < 64; ++c0)
      acc = fmaf(wrow[c0], wc[c0 * 64], acc);
    wsb[((kk >> 3) * 64 + c) * 8 + (kk & 7)] = (__bf16)acc;
  } else if (bid < 40) {
    int gid = (bid - 24) * 256 + tid;   // 0..4095
    int kk = gid >> 6;
    int c  = gid & 63;
    wsb[6144 + ((kk >> 3) * 64 + c) * 8 + (kk & 7)] = (__bf16)Wk[kk * 64 + c];
  } else if (bid < 56) {
    int gid = (bid - 40) * 256 + tid;
    int kk = gid >> 6;
    int c  = gid & 63;
    wsb[10240 + ((kk >> 3) * 64 + c) * 8 + (kk & 7)] = (__bf16)Wv[kk * 64 + c];
  } else if (tid < 64) {
    int c = tid;
    float s[3];
    for (int dt = 0; dt < 3; ++dt) {
      const float* wc = W_conv + dt * 4096 + c;
      float a = 0.f;
      for (int c0 = 0; c0 < 64; ++c0) a = fmaf(b_in[c0], wc[c0 * 64], a);
      s[dt] = a;
    }
    ws[WS_BC0 + c]  = s[0];
    ws[WS_BC2 + c]  = s[2];
    ws[WS_BTOT + c] = s[0] + s[1] + s[2] + b_conv[c];
  }
}

// ---------------------------------------------------------------------------
// Attention kernel (MFMA): one block = one sequence, 4 waves.
// conv GEMM: M=48(t) N=64(c) K=96, A-frags straight from global x (im2col),
//   B-frags = pre-swizzled WccB.  C-layout: col=lane&15, row=quad*4+reg.
// k/v GEMMs: M=48 N=64 K=64, A-frags = h1 bf16 from LDS (ds_read_b128),
//   B-frags = WkB/WvB.  Then scalar q/scores/softmax/ctx (tiny).
// LDS 30.8 KB -> 5 blocks/CU.
// ---------------------------------------------------------------------------
__global__ __launch_bounds__(256) void attn_kernel(
    const float* __restrict__ x,
    const float* __restrict__ Wq, const float* __restrict__ bq,
    const float* __restrict__ bk, const float* __restrict__ bv,
    const float* __restrict__ ws, float* __restrict__ ctx)
{
  __shared__ __bf16 h1[48 * 64];
  __shared__ float  kb[48 * 65];
  __shared__ float  vb[48 * 65];
  __shared__ float  qv[64];
  __shared__ float  sc[48];

  const int tid  = threadIdx.x;
  const int seq  = blockIdx.x;
  const int lane = tid & 63;
  const int wv   = tid >> 6;        // wave id = N-tile
  const int m16  = lane & 15;
  const int quad = lane >> 4;
  const int c    = wv * 16 + m16;   // this lane's output column (n)

  const __bf16* wsb  = (const __bf16*)ws;
  const bf16x8* WccB = (const bf16x8*)(wsb);
  const bf16x8* WkB  = (const bf16x8*)(wsb + 6144);
  const bf16x8* WvB  = (const bf16x8*)(wsb + 10240);
  const float*  wsf  = ws;

  // ---- conv GEMM: 3 M-tiles per wave, K=96 (3 MFMA k-steps) ----
  f32x4 acc0 = zero4(), acc1 = zero4(), acc2 = zero4();
  const float* xseq = x + (size_t)seq * (TT * EE);
  #pragma unroll
  for (int ks = 0; ks < 3; ++ks) {
    bf16x8 bfrag = WccB[(ks * 4 + quad) * 64 + c];
    #pragma unroll
    for (int mt = 0; mt < 3; ++mt) {
      int tg = mt * 16 + m16 + ks - 1;       // global x row for this A-frag
      bf16x8 afrag;
      if (tg >= 0 && tg < 48) {
        const float* ap = xseq + tg * 32 + quad * 8;
        float4 a0 = *(const float4*)ap;
        float4 a1 = *(const float4*)(ap + 4);
        afrag[0] = (__bf16)a0.x; afrag[1] = (__bf16)a0.y;
        afrag[2] = (__bf16)a0.z; afrag[3] = (__bf16)a0.w;
        afrag[4] = (__bf16)a1.x; afrag[5] = (__bf16)a1.y;
        afrag[6] = (__bf16)a1.z; afrag[7] = (__bf16)a1.w;
      } else {
        #pragma unroll
        for (int j = 0; j < 8; ++j) afrag[j] = (__bf16)0.f;
      }
      f32x4& a = (mt == 0) ? acc0 : (mt == 1) ? acc1 : acc2;
      a = __builtin_amdgcn_mfma_f32_16x16x32_bf16(afrag, bfrag, a, 0, 0, 0);
    }
  }
  // conv epilogue: bias (+pad-row correction), relu, store bf16 to LDS
  {
    float bb  = wsf[WS_BTOT + c];
    float b0  = wsf[WS_BC0 + c];
    float b2  = wsf[WS_BC2 + c];
    #pragma unroll
    for (int mt = 0; mt < 3; ++mt) {
      const f32x4& a = (mt == 0) ? acc0 : (mt == 1) ? acc1 : acc2;
      #pragma unroll
      for (int r = 0; r < 4; ++r) {
        int t = mt * 16 + quad * 4 + r;
        float v = a[r] + bb;
        if (t == 0)  v -= b0;
        if (t == 47) v -= b2;
        h1[t * 64 + c] = (__bf16)fmaxf(v, 0.f);
      }
    }
  }
  __syncthreads();

  // ---- k and v GEMMs: K=64 (2 k-steps), A-frags shared between k and v ----
  f32x4 ka0 = zero4(), ka1 = zero4(), ka2 = zero4();
  f32x4 va0 = zero4(), va1 = zero4(), va2 = zero4();
  #pragma unroll
  for (int ks = 0; ks < 2; ++ks) {
    bf16x8 bk8 = WkB[(ks * 4 + quad) * 64 + c];
    bf16x8 bv8 = WvB[(ks * 4 + quad) * 64 + c];
    #pragma unroll
    for (int mt = 0; mt < 3; ++mt) {
      bf16x8 a8 = *(const bf16x8*)&h1[(mt * 16 + m16) * 64 + ks * 32 + quad * 8];
      f32x4& ak = (mt == 0) ? ka0 : (mt == 1) ? ka1 : ka2;
      f32x4& av = (mt == 0) ? va0 : (mt == 1) ? va1 : va2;
      ak = __builtin_amdgcn_mfma_f32_16x16x32_bf16(a8, bk8, ak, 0, 0, 0);
      av = __builtin_amdgcn_mfma_f32_16x16x32_bf16(a8, bv8, av, 0, 0, 0);
    }
  }
  {
    float bkc = bk[c], bvc = bv[c];
    #pragma unroll
    for (int mt = 0; mt < 3; ++mt) {
      const f32x4& ak = (mt == 0) ? ka0 : (mt == 1) ? ka1 : ka2;
      const f32x4& av = (mt == 0) ? va0 : (mt == 1) ? va1 : va2;
      #pragma unroll
      for (int r = 0; r < 4; ++r) {
        int t = mt * 16 + quad * 4 + r;
        kb[t * 65 + c] = ak[r] + bkc;
        vb[t * 65 + c] = av[r] + bvc;
      }
    }
  }
  __syncthreads();

  // ---- q at t=47 (wave 0) ----
  if (tid < 64) {
    int cc = tid;
    float a0 = bq[cc], a1 = 0.f;
    #pragma unroll 8
    for (int k = 0; k < 64; k += 2) {
      a0 = fmaf((float)h1[47 * 64 + k],     Wq[k * 64 + cc],       a0);
      a1 = fmaf((float)h1[47 * 64 + k + 1], Wq[(k + 1) * 64 + cc], a1);
    }
    qv[cc] = a0 + a1;
  }
  __syncthreads();

  // ---- scores + softmax (wave 0, in-register across the wave) ----
  if (tid < 64) {
    float val = -INFINITY;
    if (tid < 48) {
      const float* kr = kb + tid * 65;
      float a0 = 0.f, a1 = 0.f, a2 = 0.f, a3 = 0.f;
      #pragma unroll 4
      for (int k = 0; k < 64; k += 4) {
        a0 = fmaf(qv[k],     kr[k],     a0);
        a1 = fmaf(qv[k + 1], kr[k + 1], a1);
        a2 = fmaf(qv[k + 2], kr[k + 2], a2);
        a3 = fmaf(qv[k + 3], kr[k + 3], a3);
      }
      val = (a0 + a1 + a2 + a3) * 0.125f;   // / sqrt(64)
    }
    float mx = val;
    #pragma unroll
    for (int m = 32; m > 0; m >>= 1) mx = fmaxf(mx, __shfl_xor(mx, m, 64));
    float p = __expf(val - mx);             // lanes >=48: exp(-inf)=0
    float sum = p;
    #pragma unroll
    for (int m = 32; m > 0; m >>= 1) sum += __shfl_xor(sum, m, 64);
    if (tid < 48) sc[tid] = p / sum;
  }
  __syncthreads();

  // ---- ctx_last = attn . v (wave 0) ----
  if (tid < 64) {
    int cc = tid;
    float a0 = 0.f, a1 = 0.f;
    #pragma unroll 8
    for (int s = 0; s < 48; s += 2) {
      a0 = fmaf(sc[s],     vb[s * 65 + cc],       a0);
      a1 = fmaf(sc[s + 1], vb[(s + 1) * 65 + cc], a1);
    }
    ctx[(size_t)seq * 64 + cc] = a0 + a1;
  }
}

// ---------------------------------------------------------------------------
// MLP kernel: 32 rows/block (1024 blocks), weights amortized 32x, tiled GEMM.
// Writes the (B, NPRED, N) transpose directly.  (fp32; MFMA next round.)
// ---------------------------------------------------------------------------
__global__ __launch_bounds__(256) void mlp_kernel(
    const float* __restrict__ ctx,
    const float* __restrict__ W1, const float* __restrict__ b1,
    const float* __restrict__ W2, const float* __restrict__ b2,
    const float* __restrict__ W3, const float* __restrict__ b3,
    float* __restrict__ out)
{
  __shared__ __align__(16) float Xs[32 * 64];
  __shared__ float z1[32 * 256];
  __shared__ float z2[32 * 128];
  const int tid = threadIdx.x;
  const int r0  = blockIdx.x * 32;

  const float4* xg = reinterpret_cast<const float4*>(ctx + (size_t)r0 * 64);
  float4* xl = reinterpret_cast<float4*>(Xs);
  xl[tid]       = xg[tid];
  xl[256 + tid] = xg[256 + tid];
  __syncthreads();

  // layer 1: 32x256, K=64. thread tile 4 rows x 8 cols.
  {
    const int cg = tid & 31, rg = tid >> 5;
    const int c8 = cg * 8, r4 = rg * 4;
    float a[4][8] = {};
    #pragma unroll 2
    for (int k = 0; k < 64; ++k) {
      float4 wA = *reinterpret_cast<const float4*>(W1 + k * 256 + c8);
      float4 wB = *reinterpret_cast<const float4*>(W1 + k * 256 + c8 + 4);
      #pragma unroll
      for (int j = 0; j < 4; ++j) {
        float xv = Xs[(r4 + j) * 64 + k];
        a[j][0] = fmaf(xv, wA.x, a[j][0]);
        a[j][1] = fmaf(xv, wA.y, a[j][1]);
        a[j][2] = fmaf(xv, wA.z, a[j][2]);
        a[j][3] = fmaf(xv, wA.w, a[j][3]);
        a[j][4] = fmaf(xv, wB.x, a[j][4]);
        a[j][5] = fmaf(xv, wB.y, a[j][5]);
        a[j][6] = fmaf(xv, wB.z, a[j][6]);
        a[j][7] = fmaf(xv, wB.w, a[j][7]);
      }
    }
    #pragma unroll
    for (int j = 0; j < 4; ++j)
      #pragma unroll
      for (int i = 0; i < 8; ++i)
        z1[(r4 + j) * 256 + c8 + i] = fmaxf(a[j][i] + b1[c8 + i], 0.f);
  }
  __syncthreads();

  // layer 2: 32x128, K=256. thread tile 4 rows x 4 cols.
  {
    const int cg = tid & 31, rg = tid >> 5;
    const int c4 = cg * 4, r4 = rg * 4;
    float a[4][4] = {};
    #pragma unroll 2
    for (int k = 0; k < 256; ++k) {
      float4 w = *reinterpret_cast<const float4*>(W2 + k * 128 + c4);
      #pragma unroll
      for (int j = 0; j < 4; ++j) {
        float zv = z1[(r4 + j) * 256 + k];
        a[j][0] = fmaf(zv, w.x, a[j][0]);
        a[j][1] = fmaf(zv, w.y, a[j][1]);
        a[j][2] = fmaf(zv, w.z, a[j][2]);
        a[j][3] = fmaf(zv, w.w, a[j][3]);
      }
    }
    #pragma unroll
    for (int j = 0; j < 4; ++j)
      #pragma unroll
      for (int i = 0; i < 4; ++i)
        z2[(r4 + j) * 128 + c4 + i] = fmaxf(a[j][i] + b2[c4 + i], 0.f);
  }
  __syncthreads();

  // layer 3 (32x12, K=128) + transposed store: out[b*12*2048 + p*2048 + n]
  for (int o = tid; o < 32 * NP; o += 256) {
    int r = o / NP, p = o - r * NP;
    float a = b3[p];
    const float* zr = z2 + r * 128;
    #pragma unroll 4
    for (int k = 0; k < 128; ++k)
      a = fmaf(zr[k], W3[k * NP + p], a);
    int row = r0 + r;
    int bb = row >> 11, nn = row & 2047;
    out[(size_t)bb * (NP * 2048) + p * 2048 + nn] = a;
  }
}

// ---------------------------------------------------------------------------
extern "C" void kernel_launch(void* const* d_in, const int* in_sizes, int n_in,
                              void* d_out, int out_size, void* d_ws, size_t ws_size,
                              hipStream_t stream) {
  const float* x      = (const float*)d_in[0];
  const float* W_in   = (const float*)d_in[1];
  const float* b_in   = (const float*)d_in[2];
  const float* W_conv = (const float*)d_in[3];
  const float* b_conv = (const float*)d_in[4];
  const float* Wq     = (const float*)d_in[5];
  const float* bq     = (const float*)d_in[6];
  const float* Wk     = (const float*)d_in[7];
  const float* bk     = (const float*)d_in[8];
  const float* Wv     = (const float*)d_in[9];
  const float* bv     = (const float*)d_in[10];
  const float* W1     = (const float*)d_in[11];
  const float* b1     = (const float*)d_in[12];
  const float* W2     = (const float*)d_in[13];
  const float* b2     = (const float*)d_in[14];
  const float* W3     = (const float*)d_in[15];
  const float* b3     = (const float*)d_in[16];
  float* ws  = (float*)d_ws;
  float* out = (float*)d_out;

  prep_kernel<<<57, 256, 0, stream>>>(W_in, b_in, W_conv, b_conv, Wk, Wv, ws);
  attn_kernel<<<NSEQ, 256, 0, stream>>>(x, Wq, bq, bk, bv, ws, ws + WS_CTX);
  mlp_kernel<<<NSEQ / 32, 256, 0, stream>>>(ws + WS_CTX, W1, b1, W2, b2, W3, b3, out);
}

// Round 3
// 620.619 us; speedup vs baseline: 2.2847x; 1.1733x over previous
//
#include <hip/hip_runtime.h>
#include <math.h>

// Problem constants
#define TT 48
#define NSEQ (16*2048)
#define NP 12

// MFMA fragment types (gfx950: mfma_f32_16x16x32_bf16)
typedef __bf16 bf16x8 __attribute__((ext_vector_type(8)));
typedef float  f32x4  __attribute__((ext_vector_type(4)));

// ws layout.
// bf16 region (ws viewed as __bf16*), all B-frag swizzled [((k>>3)*N + n)*8 + (k&7)]:
//   [0)      WccB  96x64   (folded W_in @ W_conv)
//   [6144)   WkB   64x64
//   [10240)  WvB   64x64
//   [14336)  WqB   64x64
//   [18432)  W1B   64x256
//   [34816)  W2B   256x128   -> ends 67584 bf16 == float idx 33792
// float region (ws viewed as float*):
//   [33792)  btot 64   (bc0+bc1+bc2+b_conv)
//   [33856)  bc0  64
//   [33920)  bc2  64
//   [33984)  ctx  32768*64
#define OFF_WCC 0
#define OFF_WK  6144
#define OFF_WV  10240
#define OFF_WQ  14336
#define OFF_W1  18432
#define OFF_W2  34816
#define WS_BTOT 33792
#define WS_BC0  33856
#define WS_BC2  33920
#define WS_CTX  33984

__device__ __forceinline__ f32x4 zero4() {
  f32x4 z; z[0] = 0.f; z[1] = 0.f; z[2] = 0.f; z[3] = 0.f; return z;
}

// ---------------------------------------------------------------------------
// Prep: fold W_in into conv weights; convert all GEMM weights to bf16 in
// B-fragment-swizzled order (one 16B load per lane per frag).
// ---------------------------------------------------------------------------
__global__ __launch_bounds__(256) void prep_kernel(
    const float* __restrict__ W_in, const float* __restrict__ b_in,
    const float* __restrict__ W_conv, const float* __restrict__ b_conv,
    const float* __restrict__ Wk, const float* __restrict__ Wv,
    const float* __restrict__ Wq, const float* __restrict__ W1,
    const float* __restrict__ W2, float* __restrict__ ws)
{
  __bf16* wsb = (__bf16*)ws;
  const int tid = threadIdx.x;
  const int bid = blockIdx.x;
  if (bid < 24) {                       // WccB: fold W_in into W_conv
    int gid = bid * 256 + tid;          // 0..6143
    int kk = gid >> 6;                  // 0..95
    int c  = gid & 63;
    int dt = kk >> 5;
    int e  = kk & 31;
    const float* wrow = W_in + e * 64;
    const float* wc   = W_conv + dt * 4096 + c;
    float acc = 0.f;
    #pragma unroll 8
    for (int c0 = 0; c0 < 64; ++c0)
      acc = fmaf(wrow[c0], wc[c0 * 64], acc);
    wsb[OFF_WCC + ((kk >> 3) * 64 + c) * 8 + (kk & 7)] = (__bf16)acc;
  } else if (bid < 40) {                // WkB
    int gid = (bid - 24) * 256 + tid;
    int kk = gid >> 6, c = gid & 63;
    wsb[OFF_WK + ((kk >> 3) * 64 + c) * 8 + (kk & 7)] = (__bf16)Wk[kk * 64 + c];
  } else if (bid < 56) {                // WvB
    int gid = (bid - 40) * 256 + tid;
    int kk = gid >> 6, c = gid & 63;
    wsb[OFF_WV + ((kk >> 3) * 64 + c) * 8 + (kk & 7)] = (__bf16)Wv[kk * 64 + c];
  } else if (bid < 72) {                // WqB
    int gid = (bid - 56) * 256 + tid;
    int kk = gid >> 6, c = gid & 63;
    wsb[OFF_WQ + ((kk >> 3) * 64 + c) * 8 + (kk & 7)] = (__bf16)Wq[kk * 64 + c];
  } else if (bid < 136) {               // W1B (64x256)
    int gid = (bid - 72) * 256 + tid;   // 0..16383
    int kk = gid >> 8, n = gid & 255;
    wsb[OFF_W1 + ((kk >> 3) * 256 + n) * 8 + (kk & 7)] = (__bf16)W1[kk * 256 + n];
  } else if (bid < 264) {               // W2B (256x128)
    int gid = (bid - 136) * 256 + tid;  // 0..32767
    int kk = gid >> 7, n = gid & 127;
    wsb[OFF_W2 + ((kk >> 3) * 128 + n) * 8 + (kk & 7)] = (__bf16)W2[kk * 128 + n];
  } else if (tid < 64) {                // bias folding
    int c = tid;
    float s[3];
    for (int dt = 0; dt < 3; ++dt) {
      const float* wc = W_conv + dt * 4096 + c;
      float a = 0.f;
      for (int c0 = 0; c0 < 64; ++c0) a = fmaf(b_in[c0], wc[c0 * 64], a);
      s[dt] = a;
    }
    ws[WS_BC0 + c]  = s[0];
    ws[WS_BC2 + c]  = s[2];
    ws[WS_BTOT + c] = s[0] + s[1] + s[2] + b_conv[c];
  }
}

// ---------------------------------------------------------------------------
// Attention kernel: one block = one sequence, 4 waves.  All heavy GEMMs via
// MFMA (conv K=96, k/v K=64, q = rows-32..47 tile only, fused into kv loop).
// Tail phases (scores/softmax/ctx) distributed across waves — no serial wave0
// loops.  LDS 32.6 KB -> 5 blocks/CU.
// ---------------------------------------------------------------------------
__global__ __launch_bounds__(256) void attn_kernel(
    const float* __restrict__ x,
    const float* __restrict__ bq, const float* __restrict__ bk,
    const float* __restrict__ bv,
    const float* __restrict__ ws, float* __restrict__ ctx)
{
  __shared__ __align__(16) __bf16 h1[48 * 64];   // 6144 B
  __shared__ float  kb[48 * 65];                 // 12480 B
  __shared__ float  vb[48 * 65];                 // 12480 B
  __shared__ float  qv[64];
  __shared__ float  sc[48];
  __shared__ float  ctxp[4 * 64];

  const int tid  = threadIdx.x;
  const int seq  = blockIdx.x;
  const int lane = tid & 63;
  const int wv   = tid >> 6;        // wave id = N-tile
  const int m16  = lane & 15;
  const int quad = lane >> 4;
  const int c    = wv * 16 + m16;   // this lane's output column

  const __bf16* wsb  = (const __bf16*)ws;
  const bf16x8* WccB = (const bf16x8*)(wsb + OFF_WCC);
  const bf16x8* WkB  = (const bf16x8*)(wsb + OFF_WK);
  const bf16x8* WvB  = (const bf16x8*)(wsb + OFF_WV);
  const bf16x8* WqB  = (const bf16x8*)(wsb + OFF_WQ);
  const float*  wsf  = ws;

  // ---- conv GEMM: M=48 N=64 K=96, A-frags straight from global x ----
  f32x4 cacc[3] = {zero4(), zero4(), zero4()};
  const float* xseq = x + (size_t)seq * (TT * 32);
  #pragma unroll
  for (int ks = 0; ks < 3; ++ks) {
    bf16x8 bfrag = WccB[(ks * 4 + quad) * 64 + c];
    #pragma unroll
    for (int mt = 0; mt < 3; ++mt) {
      int tg = mt * 16 + m16 + ks - 1;
      bf16x8 afrag;
      if (tg >= 0 && tg < 48) {
        const float* ap = xseq + tg * 32 + quad * 8;
        float4 a0 = *(const float4*)ap;
        float4 a1 = *(const float4*)(ap + 4);
        afrag[0] = (__bf16)a0.x; afrag[1] = (__bf16)a0.y;
        afrag[2] = (__bf16)a0.z; afrag[3] = (__bf16)a0.w;
        afrag[4] = (__bf16)a1.x; afrag[5] = (__bf16)a1.y;
        afrag[6] = (__bf16)a1.z; afrag[7] = (__bf16)a1.w;
      } else {
        #pragma unroll
        for (int j = 0; j < 8; ++j) afrag[j] = (__bf16)0.f;
      }
      cacc[mt] = __builtin_amdgcn_mfma_f32_16x16x32_bf16(afrag, bfrag, cacc[mt], 0, 0, 0);
    }
  }
  { // epilogue: bias (+pad-row fix), relu, bf16 -> LDS
    float bb = wsf[WS_BTOT + c];
    float b0 = wsf[WS_BC0 + c];
    float b2 = wsf[WS_BC2 + c];
    #pragma unroll
    for (int mt = 0; mt < 3; ++mt)
      #pragma unroll
      for (int r = 0; r < 4; ++r) {
        int t = mt * 16 + quad * 4 + r;
        float v = cacc[mt][r] + bb;
        if (t == 0)  v -= b0;
        if (t == 47) v -= b2;
        h1[t * 64 + c] = (__bf16)fmaxf(v, 0.f);
      }
  }
  __syncthreads();

  // ---- k, v GEMMs (M=48 N=64 K=64) + q tile (rows 32..47) fused ----
  f32x4 ka[3] = {zero4(), zero4(), zero4()};
  f32x4 va[3] = {zero4(), zero4(), zero4()};
  f32x4 qa = zero4();
  #pragma unroll
  for (int ks = 0; ks < 2; ++ks) {
    bf16x8 bk8 = WkB[(ks * 4 + quad) * 64 + c];
    bf16x8 bv8 = WvB[(ks * 4 + quad) * 64 + c];
    bf16x8 bq8 = WqB[(ks * 4 + quad) * 64 + c];
    #pragma unroll
    for (int mt = 0; mt < 3; ++mt) {
      bf16x8 a8 = *(const bf16x8*)&h1[(mt * 16 + m16) * 64 + ks * 32 + quad * 8];
      ka[mt] = __builtin_amdgcn_mfma_f32_16x16x32_bf16(a8, bk8, ka[mt], 0, 0, 0);
      va[mt] = __builtin_amdgcn_mfma_f32_16x16x32_bf16(a8, bv8, va[mt], 0, 0, 0);
      if (mt == 2)
        qa = __builtin_amdgcn_mfma_f32_16x16x32_bf16(a8, bq8, qa, 0, 0, 0);
    }
  }
  {
    float bkc = bk[c], bvc = bv[c];
    #pragma unroll
    for (int mt = 0; mt < 3; ++mt)
      #pragma unroll
      for (int r = 0; r < 4; ++r) {
        int t = mt * 16 + quad * 4 + r;
        kb[t * 65 + c] = ka[mt][r] + bkc;
        vb[t * 65 + c] = va[mt][r] + bvc;
      }
    if (quad == 3) qv[c] = qa[3] + bq[c];   // row 47 = quad 3, reg 3
  }
  __syncthreads();

  // ---- scores: waves 0..2, 16 t's each; 4 lanes per t over c-chunks ----
  if (wv < 3) {
    int t = wv * 16 + (lane >> 2);
    int g = lane & 3;
    const float* kr = kb + t * 65 + g * 16;
    const float* qr = qv + g * 16;
    float a0 = 0.f, a1 = 0.f, a2 = 0.f, a3 = 0.f;
    #pragma unroll
    for (int i = 0; i < 16; i += 4) {
      a0 = fmaf(qr[i],     kr[i],     a0);
      a1 = fmaf(qr[i + 1], kr[i + 1], a1);
      a2 = fmaf(qr[i + 2], kr[i + 2], a2);
      a3 = fmaf(qr[i + 3], kr[i + 3], a3);
    }
    float s = (a0 + a1) + (a2 + a3);
    s += __shfl_xor(s, 1, 64);
    s += __shfl_xor(s, 2, 64);
    if (g == 0) sc[t] = s * 0.125f;   // / sqrt(64)
  }
  __syncthreads();

  // ---- softmax over 48 (wave 0, in-register) ----
  if (tid < 64) {
    float val = (tid < 48) ? sc[tid] : -INFINITY;
    float mx = val;
    #pragma unroll
    for (int m = 32; m > 0; m >>= 1) mx = fmaxf(mx, __shfl_xor(mx, m, 64));
    float p = __expf(val - mx);
    float sum = p;
    #pragma unroll
    for (int m = 32; m > 0; m >>= 1) sum += __shfl_xor(sum, m, 64);
    if (tid < 48) sc[tid] = p / sum;
  }
  __syncthreads();

  // ---- ctx partials: wave w sums t in [12w, 12w+12) for all 64 c ----
  {
    const int t0 = wv * 12;
    float a = 0.f;
    #pragma unroll
    for (int j = 0; j < 12; ++j)
      a = fmaf(sc[t0 + j], vb[(t0 + j) * 65 + lane], a);
    ctxp[wv * 64 + lane] = a;
  }
  __syncthreads();
  if (tid < 64)
    ctx[(size_t)seq * 64 + tid] =
        (ctxp[tid] + ctxp[64 + tid]) + (ctxp[128 + tid] + ctxp[192 + tid]);
}

// ---------------------------------------------------------------------------
// MLP kernel (MFMA layers 1-2, fp32 layer 3): 32 rows/block, 1024 blocks.
// z1 stored bf16 with row stride 264 (+8 pad -> 4-bank row shift, 2-way-free
// frag reads).  z2 fp32 stride 132.  LDS 37.9 KB -> 4 blocks/CU.
// ---------------------------------------------------------------------------
__global__ __launch_bounds__(256) void mlp_kernel(
    const float* __restrict__ ctx, const float* __restrict__ ws,
    const float* __restrict__ b1, const float* __restrict__ b2,
    const float* __restrict__ W3, const float* __restrict__ b3,
    float* __restrict__ out)
{
  __shared__ __align__(16) __bf16 Xs[32 * 64];    // 4096 B
  __shared__ __align__(16) __bf16 z1[32 * 264];   // 16896 B
  __shared__ float z2[32 * 132];                  // 16896 B

  const int tid  = threadIdx.x;
  const int r0   = blockIdx.x * 32;
  const int lane = tid & 63;
  const int wv   = tid >> 6;
  const int m16  = lane & 15;
  const int quad = lane >> 4;

  const __bf16* wsb = (const __bf16*)ws;
  const bf16x8* W1B = (const bf16x8*)(wsb + OFF_W1);
  const bf16x8* W2B = (const bf16x8*)(wsb + OFF_W2);

  // load 32 ctx rows, cast bf16 -> Xs
  {
    const float4* xg = (const float4*)(ctx + (size_t)r0 * 64);
    float4 a0 = xg[tid * 2], a1 = xg[tid * 2 + 1];
    __bf16* d = &Xs[tid * 8];
    d[0] = (__bf16)a0.x; d[1] = (__bf16)a0.y; d[2] = (__bf16)a0.z; d[3] = (__bf16)a0.w;
    d[4] = (__bf16)a1.x; d[5] = (__bf16)a1.y; d[6] = (__bf16)a1.z; d[7] = (__bf16)a1.w;
  }
  __syncthreads();

  // ---- layer 1: M=32 N=256 K=64; wave covers n in [wv*64, wv*64+64) ----
  {
    bf16x8 a8[2][2];
    #pragma unroll
    for (int mt = 0; mt < 2; ++mt)
      #pragma unroll
      for (int ks = 0; ks < 2; ++ks)
        a8[mt][ks] = *(const bf16x8*)&Xs[(mt * 16 + m16) * 64 + ks * 32 + quad * 8];
    f32x4 acc[2][4];
    #pragma unroll
    for (int mt = 0; mt < 2; ++mt)
      #pragma unroll
      for (int nt = 0; nt < 4; ++nt) acc[mt][nt] = zero4();
    #pragma unroll
    for (int nt = 0; nt < 4; ++nt) {
      int n = wv * 64 + nt * 16 + m16;
      #pragma unroll
      for (int ks = 0; ks < 2; ++ks) {
        bf16x8 b8 = W1B[(ks * 4 + quad) * 256 + n];
        #pragma unroll
        for (int mt = 0; mt < 2; ++mt)
          acc[mt][nt] = __builtin_amdgcn_mfma_f32_16x16x32_bf16(a8[mt][ks], b8, acc[mt][nt], 0, 0, 0);
      }
    }
    #pragma unroll
    for (int nt = 0; nt < 4; ++nt) {
      int n = wv * 64 + nt * 16 + m16;
      float bb = b1[n];
      #pragma unroll
      for (int mt = 0; mt < 2; ++mt)
        #pragma unroll
        for (int r = 0; r < 4; ++r) {
          int t = mt * 16 + quad * 4 + r;
          z1[t * 264 + n] = (__bf16)fmaxf(acc[mt][nt][r] + bb, 0.f);
        }
    }
  }
  __syncthreads();

  // ---- layer 2: M=32 N=128 K=256; wave covers n in [wv*32, wv*32+32) ----
  {
    f32x4 acc[2][2];
    #pragma unroll
    for (int mt = 0; mt < 2; ++mt)
      #pragma unroll
      for (int nt = 0; nt < 2; ++nt) acc[mt][nt] = zero4();
    #pragma unroll 2
    for (int ks = 0; ks < 8; ++ks) {
      bf16x8 a0 = *(const bf16x8*)&z1[m16 * 264 + ks * 32 + quad * 8];
      bf16x8 a1 = *(const bf16x8*)&z1[(16 + m16) * 264 + ks * 32 + quad * 8];
      #pragma unroll
      for (int nt = 0; nt < 2; ++nt) {
        bf16x8 b8 = W2B[(ks * 4 + quad) * 128 + wv * 32 + nt * 16 + m16];
        acc[0][nt] = __builtin_amdgcn_mfma_f32_16x16x32_bf16(a0, b8, acc[0][nt], 0, 0, 0);
        acc[1][nt] = __builtin_amdgcn_mfma_f32_16x16x32_bf16(a1, b8, acc[1][nt], 0, 0, 0);
      }
    }
    #pragma unroll
    for (int nt = 0; nt < 2; ++nt) {
      int n = wv * 32 + nt * 16 + m16;
      float bb = b2[n];
      #pragma unroll
      for (int mt = 0; mt < 2; ++mt)
        #pragma unroll
        for (int r = 0; r < 4; ++r) {
          int t = mt * 16 + quad * 4 + r;
          z2[t * 132 + n] = fmaxf(acc[mt][nt][r] + bb, 0.f);
        }
    }
  }
  __syncthreads();

  // ---- layer 3 (fp32, 32x12 K=128) + transposed store out[b][p][n] ----
  for (int o = tid; o < 32 * NP; o += 256) {
    int r = o / NP, p = o - r * NP;
    float a = b3[p];
    const float* zr = z2 + r * 132;
    #pragma unroll 4
    for (int k = 0; k < 128; ++k)
      a = fmaf(zr[k], W3[k * NP + p], a);
    int row = r0 + r;
    int bb = row >> 11, nn = row & 2047;
    out[(size_t)bb * (NP * 2048) + p * 2048 + nn] = a;
  }
}

// ---------------------------------------------------------------------------
extern "C" void kernel_launch(void* const* d_in, const int* in_sizes, int n_in,
                              void* d_out, int out_size, void* d_ws, size_t ws_size,
                              hipStream_t stream) {
  const float* x      = (const float*)d_in[0];
  const float* W_in   = (const float*)d_in[1];
  const float* b_in   = (const float*)d_in[2];
  const float* W_conv = (const float*)d_in[3];
  const float* b_conv = (const float*)d_in[4];
  const float* Wq     = (const float*)d_in[5];
  const float* bq     = (const float*)d_in[6];
  const float* Wk     = (const float*)d_in[7];
  const float* bk     = (const float*)d_in[8];
  const float* Wv     = (const float*)d_in[9];
  const float* bv     = (const float*)d_in[10];
  const float* W1     = (const float*)d_in[11];
  const float* b1     = (const float*)d_in[12];
  const float* W2     = (const float*)d_in[13];
  const float* b2     = (const float*)d_in[14];
  const float* W3     = (const float*)d_in[15];
  const float* b3     = (const float*)d_in[16];
  float* ws  = (float*)d_ws;
  float* out = (float*)d_out;

  prep_kernel<<<265, 256, 0, stream>>>(W_in, b_in, W_conv, b_conv, Wk, Wv, Wq, W1, W2, ws);
  attn_kernel<<<NSEQ, 256, 0, stream>>>(x, bq, bk, bv, ws, ws + WS_CTX);
  mlp_kernel<<<NSEQ / 32, 256, 0, stream>>>(ws + WS_CTX, ws, b1, b2, W3, b3, out);
}

// Round 4
// 399.099 us; speedup vs baseline: 3.5528x; 1.5551x over previous
//
#include <hip/hip_runtime.h>
#include <math.h>

// Problem constants
#define TT 48
#define NSEQ (16*2048)
#define NP 12

// MFMA fragment types (gfx950: mfma_f32_16x16x32_bf16)
typedef __bf16 bf16x8 __attribute__((ext_vector_type(8)));
typedef float  f32x4  __attribute__((ext_vector_type(4)));

// ws layout.
// bf16 region (ws viewed as __bf16*), all B-frag swizzled [((k>>3)*N + n)*8 + (k&7)]:
//   [0)      WccB  96x64   (folded W_in @ W_conv)
//   [6144)   WkB   64x64
//   [10240)  WvB   64x64
//   [14336)  WqB   64x64
//   [18432)  W1B   64x256
//   [34816)  W2B   256x128   -> ends 67584 bf16 == float idx 33792
// float region (ws viewed as float*):
//   [33792)  btot 64   (bc0+bc1+bc2+b_conv)
//   [33856)  bc0  64
//   [33920)  bc2  64
//   [33984)  ctx  32768*64
#define OFF_WCC 0
#define OFF_WK  6144
#define OFF_WV  10240
#define OFF_WQ  14336
#define OFF_W1  18432
#define OFF_W2  34816
#define WS_BTOT 33792
#define WS_BC0  33856
#define WS_BC2  33920
#define WS_CTX  33984

__device__ __forceinline__ f32x4 zero4() {
  f32x4 z; z[0] = 0.f; z[1] = 0.f; z[2] = 0.f; z[3] = 0.f; return z;
}

// ---------------------------------------------------------------------------
// Prep: fold W_in into conv weights; convert all GEMM weights to bf16 in
// B-fragment-swizzled order (one 16B load per lane per frag).
// ---------------------------------------------------------------------------
__global__ __launch_bounds__(256) void prep_kernel(
    const float* __restrict__ W_in, const float* __restrict__ b_in,
    const float* __restrict__ W_conv, const float* __restrict__ b_conv,
    const float* __restrict__ Wk, const float* __restrict__ Wv,
    const float* __restrict__ Wq, const float* __restrict__ W1,
    const float* __restrict__ W2, float* __restrict__ ws)
{
  __bf16* wsb = (__bf16*)ws;
  const int tid = threadIdx.x;
  const int bid = blockIdx.x;
  if (bid < 24) {                       // WccB: fold W_in into W_conv
    int gid = bid * 256 + tid;          // 0..6143
    int kk = gid >> 6;                  // 0..95
    int c  = gid & 63;
    int dt = kk >> 5;
    int e  = kk & 31;
    const float* wrow = W_in + e * 64;
    const float* wc   = W_conv + dt * 4096 + c;
    float acc = 0.f;
    #pragma unroll 8
    for (int c0 = 0; c0 < 64; ++c0)
      acc = fmaf(wrow[c0], wc[c0 * 64], acc);
    wsb[OFF_WCC + ((kk >> 3) * 64 + c) * 8 + (kk & 7)] = (__bf16)acc;
  } else if (bid < 40) {                // WkB
    int gid = (bid - 24) * 256 + tid;
    int kk = gid >> 6, c = gid & 63;
    wsb[OFF_WK + ((kk >> 3) * 64 + c) * 8 + (kk & 7)] = (__bf16)Wk[kk * 64 + c];
  } else if (bid < 56) {                // WvB
    int gid = (bid - 40) * 256 + tid;
    int kk = gid >> 6, c = gid & 63;
    wsb[OFF_WV + ((kk >> 3) * 64 + c) * 8 + (kk & 7)] = (__bf16)Wv[kk * 64 + c];
  } else if (bid < 72) {                // WqB
    int gid = (bid - 56) * 256 + tid;
    int kk = gid >> 6, c = gid & 63;
    wsb[OFF_WQ + ((kk >> 3) * 64 + c) * 8 + (kk & 7)] = (__bf16)Wq[kk * 64 + c];
  } else if (bid < 136) {               // W1B (64x256)
    int gid = (bid - 72) * 256 + tid;   // 0..16383
    int kk = gid >> 8, n = gid & 255;
    wsb[OFF_W1 + ((kk >> 3) * 256 + n) * 8 + (kk & 7)] = (__bf16)W1[kk * 256 + n];
  } else if (bid < 264) {               // W2B (256x128)
    int gid = (bid - 136) * 256 + tid;  // 0..32767
    int kk = gid >> 7, n = gid & 127;
    wsb[OFF_W2 + ((kk >> 3) * 128 + n) * 8 + (kk & 7)] = (__bf16)W2[kk * 128 + n];
  } else if (tid < 64) {                // bias folding
    int c = tid;
    float s[3];
    for (int dt = 0; dt < 3; ++dt) {
      const float* wc = W_conv + dt * 4096 + c;
      float a = 0.f;
      for (int c0 = 0; c0 < 64; ++c0) a = fmaf(b_in[c0], wc[c0 * 64], a);
      s[dt] = a;
    }
    ws[WS_BC0 + c]  = s[0];
    ws[WS_BC2 + c]  = s[2];
    ws[WS_BTOT + c] = s[0] + s[1] + s[2] + b_conv[c];
  }
}

// ---------------------------------------------------------------------------
// Attention kernel: ONE WAVE = ONE SEQUENCE (block = 4 independent seqs).
// No __syncthreads anywhere.  Per wave: conv (36 MFMA, A-frags straight from
// global x) -> h1 bf16 in LDS (stride 66 = conflict-free frag reads) ->
// q/k/v GEMM passes (56 MFMA) -> scores/softmax/ctx fully in registers via
// C-layout + shfl_xor reductions (m16 bits = channel, quad bits = timestep).
// LDS 25.3 KB/block -> 6 blocks/CU.
// ---------------------------------------------------------------------------
__global__ __launch_bounds__(256, 2) void attn_kernel(
    const float* __restrict__ x,
    const float* __restrict__ bq, const float* __restrict__ bk,
    const float* __restrict__ bv,
    const float* __restrict__ ws, float* __restrict__ ctx)
{
  __shared__ __bf16 h1s[4][48 * 66];   // 25344 B

  const int tid  = threadIdx.x;
  const int lane = tid & 63;
  const int wv   = tid >> 6;
  const int m16  = lane & 15;
  const int quad = lane >> 4;
  const int seq  = blockIdx.x * 4 + wv;
  __bf16* h1 = h1s[wv];

  const __bf16* wsb  = (const __bf16*)ws;
  const bf16x8* WccB = (const bf16x8*)(wsb + OFF_WCC);
  const bf16x8* WkB  = (const bf16x8*)(wsb + OFF_WK);
  const bf16x8* WvB  = (const bf16x8*)(wsb + OFF_WV);
  const bf16x8* WqB  = (const bf16x8*)(wsb + OFF_WQ);
  const float*  wsf  = ws;
  const float*  xseq = x + (size_t)seq * (TT * 32);

  // ---- conv GEMM: M=48 N=64 K=96, per-wave full N ----
  f32x4 cacc[3][4];
  #pragma unroll
  for (int mt = 0; mt < 3; ++mt)
    #pragma unroll
    for (int nt = 0; nt < 4; ++nt) cacc[mt][nt] = zero4();

  #pragma unroll
  for (int ks = 0; ks < 3; ++ks) {
    bf16x8 bf[4];
    #pragma unroll
    for (int nt = 0; nt < 4; ++nt)
      bf[nt] = WccB[(ks * 4 + quad) * 64 + nt * 16 + m16];
    #pragma unroll
    for (int mt = 0; mt < 3; ++mt) {
      const int tg = mt * 16 + m16 + ks - 1;
      const bool need_guard = (mt == 0 && ks == 0) || (mt == 2 && ks == 2);
      bf16x8 af;
      if (!need_guard || (tg >= 0 && tg < 48)) {
        const float* ap = xseq + tg * 32 + quad * 8;
        float4 a0 = *(const float4*)ap;
        float4 a1 = *(const float4*)(ap + 4);
        af[0] = (__bf16)a0.x; af[1] = (__bf16)a0.y;
        af[2] = (__bf16)a0.z; af[3] = (__bf16)a0.w;
        af[4] = (__bf16)a1.x; af[5] = (__bf16)a1.y;
        af[6] = (__bf16)a1.z; af[7] = (__bf16)a1.w;
      } else {
        #pragma unroll
        for (int j = 0; j < 8; ++j) af[j] = (__bf16)0.f;
      }
      #pragma unroll
      for (int nt = 0; nt < 4; ++nt)
        cacc[mt][nt] = __builtin_amdgcn_mfma_f32_16x16x32_bf16(af, bf[nt], cacc[mt][nt], 0, 0, 0);
    }
  }

  // conv epilogue: bias (+pad-row fix), relu, bf16 -> LDS (stride 66)
  #pragma unroll
  for (int nt = 0; nt < 4; ++nt) {
    const int c = nt * 16 + m16;
    const float bt = wsf[WS_BTOT + c];
    const float b0 = wsf[WS_BC0 + c];
    const float b2 = wsf[WS_BC2 + c];
    #pragma unroll
    for (int mt = 0; mt < 3; ++mt)
      #pragma unroll
      for (int r = 0; r < 4; ++r) {
        const int trow = mt * 16 + quad * 4 + r;
        float v = cacc[mt][nt][r] + bt;
        if (mt == 0 && r == 0 && quad == 0) v -= b0;   // t==0
        if (mt == 2 && r == 3 && quad == 3) v -= b2;   // t==47
        h1[trow * 66 + c] = (__bf16)fmaxf(v, 0.f);
      }
  }
  // within-wave LDS write->read fence (no barrier needed: one wave, one seq)
  __asm__ __volatile__("s_waitcnt lgkmcnt(0)" ::: "memory");

  // ---- A-fragments of h1 for q/k/v (shared across 3 passes) ----
  bf16x8 a8[3][2];
  #pragma unroll
  for (int mt = 0; mt < 3; ++mt)
    #pragma unroll
    for (int ks = 0; ks < 2; ++ks)
      a8[mt][ks] = *(const bf16x8*)&h1[(mt * 16 + m16) * 66 + ks * 32 + quad * 8];

  // ---- q pass: only rows 32..47 tile; broadcast row 47 via shfl ----
  float qvv[4];
  {
    f32x4 qa[4] = {zero4(), zero4(), zero4(), zero4()};
    #pragma unroll
    for (int ks = 0; ks < 2; ++ks)
      #pragma unroll
      for (int nt = 0; nt < 4; ++nt)
        qa[nt] = __builtin_amdgcn_mfma_f32_16x16x32_bf16(
            a8[2][ks], WqB[(ks * 4 + quad) * 64 + nt * 16 + m16], qa[nt], 0, 0, 0);
    #pragma unroll
    for (int nt = 0; nt < 4; ++nt) {
      // row 47 lives at quad==3, reg 3; lane m16+48 holds column nt*16+m16
      float q47 = __shfl(qa[nt][3], m16 + 48, 64);
      qvv[nt] = (q47 + bq[nt * 16 + m16]) * 0.125f;   // fold 1/sqrt(64)
    }
  }

  // ---- k pass + scores + softmax, all in registers ----
  float p[3][4];
  {
    f32x4 ka[3][4];
    #pragma unroll
    for (int mt = 0; mt < 3; ++mt)
      #pragma unroll
      for (int nt = 0; nt < 4; ++nt) ka[mt][nt] = zero4();
    #pragma unroll
    for (int ks = 0; ks < 2; ++ks) {
      bf16x8 bf[4];
      #pragma unroll
      for (int nt = 0; nt < 4; ++nt)
        bf[nt] = WkB[(ks * 4 + quad) * 64 + nt * 16 + m16];
      #pragma unroll
      for (int mt = 0; mt < 3; ++mt)
        #pragma unroll
        for (int nt = 0; nt < 4; ++nt)
          ka[mt][nt] = __builtin_amdgcn_mfma_f32_16x16x32_bf16(a8[mt][ks], bf[nt], ka[mt][nt], 0, 0, 0);
    }
    // scores: lane (m16,quad) holds kb[t = mt*16+quad*4+r][c = nt*16+m16].
    // q . (k + bk):  qb = sum_nt qvv*bk  (per-lane partial over its 4 c's)
    float qb = 0.f;
    #pragma unroll
    for (int nt = 0; nt < 4; ++nt) qb = fmaf(qvv[nt], bk[nt * 16 + m16], qb);
    float s[3][4];
    #pragma unroll
    for (int mt = 0; mt < 3; ++mt)
      #pragma unroll
      for (int r = 0; r < 4; ++r) {
        float t = qb;
        #pragma unroll
        for (int nt = 0; nt < 4; ++nt) t = fmaf(qvv[nt], ka[mt][nt][r], t);
        // reduce over the 16 m16-lanes (c dimension) within the quad group
        t += __shfl_xor(t, 1, 64);
        t += __shfl_xor(t, 2, 64);
        t += __shfl_xor(t, 4, 64);
        t += __shfl_xor(t, 8, 64);
        s[mt][r] = t;
      }
    // softmax over all 48 t (12 local + cross-quad reduce)
    float mx = -INFINITY;
    #pragma unroll
    for (int mt = 0; mt < 3; ++mt)
      #pragma unroll
      for (int r = 0; r < 4; ++r) mx = fmaxf(mx, s[mt][r]);
    mx = fmaxf(mx, __shfl_xor(mx, 16, 64));
    mx = fmaxf(mx, __shfl_xor(mx, 32, 64));
    float l = 0.f;
    #pragma unroll
    for (int mt = 0; mt < 3; ++mt)
      #pragma unroll
      for (int r = 0; r < 4; ++r) {
        float e = __expf(s[mt][r] - mx);
        p[mt][r] = e;
        l += e;
      }
    l += __shfl_xor(l, 16, 64);
    l += __shfl_xor(l, 32, 64);
    float rl = 1.f / l;
    #pragma unroll
    for (int mt = 0; mt < 3; ++mt)
      #pragma unroll
      for (int r = 0; r < 4; ++r) p[mt][r] *= rl;
  }

  // ---- v pass + ctx in registers (sum p = 1 folds bv) ----
  {
    f32x4 va[3][4];
    #pragma unroll
    for (int mt = 0; mt < 3; ++mt)
      #pragma unroll
      for (int nt = 0; nt < 4; ++nt) va[mt][nt] = zero4();
    #pragma unroll
    for (int ks = 0; ks < 2; ++ks) {
      bf16x8 bf[4];
      #pragma unroll
      for (int nt = 0; nt < 4; ++nt)
        bf[nt] = WvB[(ks * 4 + quad) * 64 + nt * 16 + m16];
      #pragma unroll
      for (int mt = 0; mt < 3; ++mt)
        #pragma unroll
        for (int nt = 0; nt < 4; ++nt)
          va[mt][nt] = __builtin_amdgcn_mfma_f32_16x16x32_bf16(a8[mt][ks], bf[nt], va[mt][nt], 0, 0, 0);
    }
    float cx[4] = {0.f, 0.f, 0.f, 0.f};
    #pragma unroll
    for (int nt = 0; nt < 4; ++nt)
      #pragma unroll
      for (int mt = 0; mt < 3; ++mt)
        #pragma unroll
        for (int r = 0; r < 4; ++r)
          cx[nt] = fmaf(p[mt][r], va[mt][nt][r], cx[nt]);
    #pragma unroll
    for (int nt = 0; nt < 4; ++nt) {
      cx[nt] += __shfl_xor(cx[nt], 16, 64);
      cx[nt] += __shfl_xor(cx[nt], 32, 64);
    }
    if (quad == 0) {
      #pragma unroll
      for (int nt = 0; nt < 4; ++nt)
        ctx[(size_t)seq * 64 + nt * 16 + m16] = cx[nt] + bv[nt * 16 + m16];
    }
  }
}

// ---------------------------------------------------------------------------
// MLP kernel (MFMA layers 1-2, fp32 layer 3): 16 rows/block, 2048 blocks
// (8/CU).  Xs padded stride 68 (old 64 was a 16-way frag-read conflict).
// Layer 3: 4 accumulators + float4 z2 reads (breaks the 128-long dep chain).
// LDS ~19 KB -> 8 blocks/CU.
// ---------------------------------------------------------------------------
__global__ __launch_bounds__(256) void mlp_kernel(
    const float* __restrict__ ctx, const float* __restrict__ ws,
    const float* __restrict__ b1, const float* __restrict__ b2,
    const float* __restrict__ W3, const float* __restrict__ b3,
    float* __restrict__ out)
{
  __shared__ __bf16 Xs[16 * 68];    // 2176 B
  __shared__ __bf16 z1[16 * 264];   // 8448 B
  __shared__ float  z2[16 * 132];   // 8448 B

  const int tid  = threadIdx.x;
  const int r0   = blockIdx.x * 16;
  const int lane = tid & 63;
  const int wv   = tid >> 6;
  const int m16  = lane & 15;
  const int quad = lane >> 4;

  const __bf16* wsb = (const __bf16*)ws;
  const bf16x8* W1B = (const bf16x8*)(wsb + OFF_W1);
  const bf16x8* W2B = (const bf16x8*)(wsb + OFF_W2);

  // load 16 ctx rows (1024 floats = 256 float4), cast bf16 -> Xs
  {
    int row = tid >> 4, c4 = (tid & 15) * 4;
    float4 a = *(const float4*)(ctx + (size_t)(r0 + row) * 64 + c4);
    __bf16* d = &Xs[row * 68 + c4];
    d[0] = (__bf16)a.x; d[1] = (__bf16)a.y; d[2] = (__bf16)a.z; d[3] = (__bf16)a.w;
  }
  __syncthreads();

  // ---- layer 1: M=16 N=256 K=64; wave covers n in [wv*64, wv*64+64) ----
  {
    bf16x8 a8[2];
    #pragma unroll
    for (int ks = 0; ks < 2; ++ks)
      a8[ks] = *(const bf16x8*)&Xs[m16 * 68 + ks * 32 + quad * 8];
    f32x4 acc[4] = {zero4(), zero4(), zero4(), zero4()};
    #pragma unroll
    for (int nt = 0; nt < 4; ++nt) {
      int n = wv * 64 + nt * 16 + m16;
      #pragma unroll
      for (int ks = 0; ks < 2; ++ks)
        acc[nt] = __builtin_amdgcn_mfma_f32_16x16x32_bf16(
            a8[ks], W1B[(ks * 4 + quad) * 256 + n], acc[nt], 0, 0, 0);
    }
    #pragma unroll
    for (int nt = 0; nt < 4; ++nt) {
      int n = wv * 64 + nt * 16 + m16;
      float bb = b1[n];
      #pragma unroll
      for (int r = 0; r < 4; ++r)
        z1[(quad * 4 + r) * 264 + n] = (__bf16)fmaxf(acc[nt][r] + bb, 0.f);
    }
  }
  __syncthreads();

  // ---- layer 2: M=16 N=128 K=256; wave covers n in [wv*32, wv*32+32) ----
  {
    f32x4 acc[2] = {zero4(), zero4()};
    #pragma unroll 2
    for (int ks = 0; ks < 8; ++ks) {
      bf16x8 a = *(const bf16x8*)&z1[m16 * 264 + ks * 32 + quad * 8];
      #pragma unroll
      for (int nt = 0; nt < 2; ++nt)
        acc[nt] = __builtin_amdgcn_mfma_f32_16x16x32_bf16(
            a, W2B[(ks * 4 + quad) * 128 + wv * 32 + nt * 16 + m16], acc[nt], 0, 0, 0);
    }
    #pragma unroll
    for (int nt = 0; nt < 2; ++nt) {
      int n = wv * 32 + nt * 16 + m16;
      float bb = b2[n];
      #pragma unroll
      for (int r = 0; r < 4; ++r)
        z2[(quad * 4 + r) * 132 + n] = fmaxf(acc[nt][r] + bb, 0.f);
    }
  }
  __syncthreads();

  // ---- layer 3 (fp32, 16x12 K=128) + transposed store out[b][p][n] ----
  if (tid < 16 * NP) {
    int r = tid / NP, pp = tid - r * NP;
    const float* zr = z2 + r * 132;
    float a0 = b3[pp], a1 = 0.f, a2 = 0.f, a3 = 0.f;
    #pragma unroll 8
    for (int k = 0; k < 128; k += 4) {
      float4 f = *(const float4*)(zr + k);
      a0 = fmaf(f.x, W3[k * NP + pp],       a0);
      a1 = fmaf(f.y, W3[(k + 1) * NP + pp], a1);
      a2 = fmaf(f.z, W3[(k + 2) * NP + pp], a2);
      a3 = fmaf(f.w, W3[(k + 3) * NP + pp], a3);
    }
    float a = (a0 + a1) + (a2 + a3);
    int row = r0 + r;
    int bb = row >> 11, nn = row & 2047;
    out[(size_t)bb * (NP * 2048) + pp * 2048 + nn] = a;
  }
}

// ---------------------------------------------------------------------------
extern "C" void kernel_launch(void* const* d_in, const int* in_sizes, int n_in,
                              void* d_out, int out_size, void* d_ws, size_t ws_size,
                              hipStream_t stream) {
  const float* x      = (const float*)d_in[0];
  const float* W_in   = (const float*)d_in[1];
  const float* b_in   = (const float*)d_in[2];
  const float* W_conv = (const float*)d_in[3];
  const float* b_conv = (const float*)d_in[4];
  const float* Wq     = (const float*)d_in[5];
  const float* bq     = (const float*)d_in[6];
  const float* Wk     = (const float*)d_in[7];
  const float* bk     = (const float*)d_in[8];
  const float* Wv     = (const float*)d_in[9];
  const float* bv     = (const float*)d_in[10];
  const float* W1     = (const float*)d_in[11];
  const float* b1     = (const float*)d_in[12];
  const float* W2     = (const float*)d_in[13];
  const float* b2     = (const float*)d_in[14];
  const float* W3     = (const float*)d_in[15];
  const float* b3     = (const float*)d_in[16];
  float* ws  = (float*)d_ws;
  float* out = (float*)d_out;

  prep_kernel<<<265, 256, 0, stream>>>(W_in, b_in, W_conv, b_conv, Wk, Wv, Wq, W1, W2, ws);
  attn_kernel<<<NSEQ / 4, 256, 0, stream>>>(x, bq, bk, bv, ws, ws + WS_CTX);
  mlp_kernel<<<NSEQ / 16, 256, 0, stream>>>(ws + WS_CTX, ws, b1, b2, W3, b3, out);
}

// Round 5
// 389.016 us; speedup vs baseline: 3.6449x; 1.0259x over previous
//
#include <hip/hip_runtime.h>
#include <hip/hip_bf16.h>
#include <math.h>

// Problem constants
#define TT 48
#define NSEQ (16*2048)
#define NP 12

// MFMA fragment types (gfx950: mfma_f32_16x16x32_bf16)
typedef __bf16 bf16x8 __attribute__((ext_vector_type(8)));
typedef float  f32x4  __attribute__((ext_vector_type(4)));

// ws layout.
// bf16 region (ws viewed as __bf16*), all B-frag swizzled [((k>>3)*N + n)*8 + (k&7)]:
//   [0)      WccB  96x64   (folded W_in @ W_conv)
//   [6144)   WkB   64x64
//   [10240)  WvB   64x64
//   [14336)  WqB   64x64
//   [18432)  W1B   64x256
//   [34816)  W2B   256x128   -> ends 67584 bf16 == float idx 33792
// float region (ws viewed as float*):
//   [33792)  btot 64   (bc0+bc1+bc2+b_conv)
//   [33856)  bc0  64
//   [33920)  bc2  64
//   [33984)  ctx  32768*64
#define OFF_WCC 0
#define OFF_WK  6144
#define OFF_WV  10240
#define OFF_WQ  14336
#define OFF_W1  18432
#define OFF_W2  34816
#define WS_BTOT 33792
#define WS_BC0  33856
#define WS_BC2  33920
#define WS_CTX  33984

__device__ __forceinline__ f32x4 zero4() {
  f32x4 z; z[0] = 0.f; z[1] = 0.f; z[2] = 0.f; z[3] = 0.f; return z;
}

union PackU { bf16x8 v; __hip_bfloat162 h[4]; };

// packed fp32x8 -> bf16x8 conversion (v_cvt_pk_bf16_f32: 4 VALU ops, not 8)
__device__ __forceinline__ bf16x8 pack8(float4 a, float4 b) {
  PackU u;
  u.h[0] = __float22bfloat162_rn(make_float2(a.x, a.y));
  u.h[1] = __float22bfloat162_rn(make_float2(a.z, a.w));
  u.h[2] = __float22bfloat162_rn(make_float2(b.x, b.y));
  u.h[3] = __float22bfloat162_rn(make_float2(b.z, b.w));
  return u.v;
}

// ---------------------------------------------------------------------------
// Prep: fold W_in into conv weights; convert all GEMM weights to bf16 in
// B-fragment-swizzled order (one 16B load per lane per frag).
// ---------------------------------------------------------------------------
__global__ __launch_bounds__(256) void prep_kernel(
    const float* __restrict__ W_in, const float* __restrict__ b_in,
    const float* __restrict__ W_conv, const float* __restrict__ b_conv,
    const float* __restrict__ Wk, const float* __restrict__ Wv,
    const float* __restrict__ Wq, const float* __restrict__ W1,
    const float* __restrict__ W2, float* __restrict__ ws)
{
  __bf16* wsb = (__bf16*)ws;
  const int tid = threadIdx.x;
  const int bid = blockIdx.x;
  if (bid < 24) {                       // WccB: fold W_in into W_conv
    int gid = bid * 256 + tid;          // 0..6143
    int kk = gid >> 6;                  // 0..95
    int c  = gid & 63;
    int dt = kk >> 5;
    int e  = kk & 31;
    const float* wrow = W_in + e * 64;
    const float* wc   = W_conv + dt * 4096 + c;
    float acc = 0.f;
    #pragma unroll 8
    for (int c0 = 0; c0 < 64; ++c0)
      acc = fmaf(wrow[c0], wc[c0 * 64], acc);
    wsb[OFF_WCC + ((kk >> 3) * 64 + c) * 8 + (kk & 7)] = (__bf16)acc;
  } else if (bid < 40) {                // WkB
    int gid = (bid - 24) * 256 + tid;
    int kk = gid >> 6, c = gid & 63;
    wsb[OFF_WK + ((kk >> 3) * 64 + c) * 8 + (kk & 7)] = (__bf16)Wk[kk * 64 + c];
  } else if (bid < 56) {                // WvB
    int gid = (bid - 40) * 256 + tid;
    int kk = gid >> 6, c = gid & 63;
    wsb[OFF_WV + ((kk >> 3) * 64 + c) * 8 + (kk & 7)] = (__bf16)Wv[kk * 64 + c];
  } else if (bid < 72) {                // WqB
    int gid = (bid - 56) * 256 + tid;
    int kk = gid >> 6, c = gid & 63;
    wsb[OFF_WQ + ((kk >> 3) * 64 + c) * 8 + (kk & 7)] = (__bf16)Wq[kk * 64 + c];
  } else if (bid < 136) {               // W1B (64x256)
    int gid = (bid - 72) * 256 + tid;   // 0..16383
    int kk = gid >> 8, n = gid & 255;
    wsb[OFF_W1 + ((kk >> 3) * 256 + n) * 8 + (kk & 7)] = (__bf16)W1[kk * 256 + n];
  } else if (bid < 264) {               // W2B (256x128)
    int gid = (bid - 136) * 256 + tid;  // 0..32767
    int kk = gid >> 7, n = gid & 127;
    wsb[OFF_W2 + ((kk >> 3) * 128 + n) * 8 + (kk & 7)] = (__bf16)W2[kk * 128 + n];
  } else if (tid < 64) {                // bias folding
    int c = tid;
    float s[3];
    for (int dt = 0; dt < 3; ++dt) {
      const float* wc = W_conv + dt * 4096 + c;
      float a = 0.f;
      for (int c0 = 0; c0 < 64; ++c0) a = fmaf(b_in[c0], wc[c0 * 64], a);
      s[dt] = a;
    }
    ws[WS_BC0 + c]  = s[0];
    ws[WS_BC2 + c]  = s[2];
    ws[WS_BTOT + c] = s[0] + s[1] + s[2] + b_conv[c];
  }
}

// ---------------------------------------------------------------------------
// Attention kernel: ONE WAVE = ONE SEQUENCE, block = 128 threads (2 seqs).
// No __syncthreads.  Register-pressure-shaped: conv and k/v passes run in two
// 32-channel halves (24 acc regs live instead of 48); x A-frags built once
// (packed cvt) and reused.  Target ~100 regs -> 4-5 waves/SIMD.
// LDS 12.7 KB/block -> LDS never binds occupancy.
// ---------------------------------------------------------------------------
__global__ __launch_bounds__(128, 4) void attn_kernel(
    const float* __restrict__ x,
    const float* __restrict__ bq, const float* __restrict__ bk,
    const float* __restrict__ bv,
    const float* __restrict__ ws, float* __restrict__ ctx)
{
  __shared__ __bf16 h1s[2][48 * 66];   // 12672 B

  const int tid  = threadIdx.x;
  const int lane = tid & 63;
  const int wv   = tid >> 6;
  const int m16  = lane & 15;
  const int quad = lane >> 4;
  const int seq  = blockIdx.x * 2 + wv;
  __bf16* h1 = h1s[wv];

  const __bf16* wsb  = (const __bf16*)ws;
  const bf16x8* WccB = (const bf16x8*)(wsb + OFF_WCC);
  const bf16x8* WkB  = (const bf16x8*)(wsb + OFF_WK);
  const bf16x8* WvB  = (const bf16x8*)(wsb + OFF_WV);
  const bf16x8* WqB  = (const bf16x8*)(wsb + OFF_WQ);
  const float*  wsf  = ws;
  const float*  xseq = x + (size_t)seq * (TT * 32);

  // ---- build all 9 x A-frags once (18 float4 loads, packed cvts) ----
  bf16x8 af[3][3];   // [mt][ks]
  #pragma unroll
  for (int mt = 0; mt < 3; ++mt)
    #pragma unroll
    for (int ks = 0; ks < 3; ++ks) {
      const int tg = mt * 16 + m16 + ks - 1;
      const bool need_guard = (mt == 0 && ks == 0) || (mt == 2 && ks == 2);
      if (!need_guard || (tg >= 0 && tg < 48)) {
        const float* ap = xseq + tg * 32 + quad * 8;
        af[mt][ks] = pack8(*(const float4*)ap, *(const float4*)(ap + 4));
      } else {
        #pragma unroll
        for (int j = 0; j < 8; ++j) af[mt][ks][j] = (__bf16)0.f;
      }
    }

  // ---- conv GEMM in two 32-channel halves (24 acc regs live) ----
  #pragma unroll
  for (int nh = 0; nh < 2; ++nh) {
    f32x4 acc[3][2];
    #pragma unroll
    for (int mt = 0; mt < 3; ++mt) { acc[mt][0] = zero4(); acc[mt][1] = zero4(); }
    #pragma unroll
    for (int ks = 0; ks < 3; ++ks) {
      bf16x8 b0 = WccB[(ks * 4 + quad) * 64 + nh * 32 + m16];
      bf16x8 b1 = WccB[(ks * 4 + quad) * 64 + nh * 32 + 16 + m16];
      #pragma unroll
      for (int mt = 0; mt < 3; ++mt) {
        acc[mt][0] = __builtin_amdgcn_mfma_f32_16x16x32_bf16(af[mt][ks], b0, acc[mt][0], 0, 0, 0);
        acc[mt][1] = __builtin_amdgcn_mfma_f32_16x16x32_bf16(af[mt][ks], b1, acc[mt][1], 0, 0, 0);
      }
    }
    // epilogue: bias (+pad-row fix), relu, bf16 -> LDS (stride 66)
    #pragma unroll
    for (int j = 0; j < 2; ++j) {
      const int c = nh * 32 + j * 16 + m16;
      const float bt = wsf[WS_BTOT + c];
      const float b0v = wsf[WS_BC0 + c];
      const float b2v = wsf[WS_BC2 + c];
      #pragma unroll
      for (int mt = 0; mt < 3; ++mt)
        #pragma unroll
        for (int r = 0; r < 4; ++r) {
          const int trow = mt * 16 + quad * 4 + r;
          float v = acc[mt][j][r] + bt;
          if (mt == 0 && r == 0 && quad == 0) v -= b0v;   // t==0
          if (mt == 2 && r == 3 && quad == 3) v -= b2v;   // t==47
          h1[trow * 66 + c] = (__bf16)fmaxf(v, 0.f);
        }
    }
  }
  // within-wave LDS write->read fence (no barrier: one wave owns its seq)
  __asm__ __volatile__("s_waitcnt lgkmcnt(0)" ::: "memory");

  // ---- A-fragments of h1 (shared by q/k/v passes) ----
  bf16x8 a8[3][2];
  #pragma unroll
  for (int mt = 0; mt < 3; ++mt)
    #pragma unroll
    for (int ks = 0; ks < 2; ++ks)
      a8[mt][ks] = *(const bf16x8*)&h1[(mt * 16 + m16) * 66 + ks * 32 + quad * 8];

  // ---- q pass: rows 32..47 tile only (16 acc regs) ----
  float qvv[4];
  {
    f32x4 qa[4] = {zero4(), zero4(), zero4(), zero4()};
    #pragma unroll
    for (int ks = 0; ks < 2; ++ks)
      #pragma unroll
      for (int nt = 0; nt < 4; ++nt)
        qa[nt] = __builtin_amdgcn_mfma_f32_16x16x32_bf16(
            a8[2][ks], WqB[(ks * 4 + quad) * 64 + nt * 16 + m16], qa[nt], 0, 0, 0);
    #pragma unroll
    for (int nt = 0; nt < 4; ++nt) {
      // row 47 = quad 3, reg 3; lane 48+m16 holds column nt*16+m16
      float q47 = __shfl(qa[nt][3], m16 + 48, 64);
      qvv[nt] = (q47 + bq[nt * 16 + m16]) * 0.125f;   // fold 1/sqrt(64)
    }
  }

  // ---- k pass (two halves, 24 acc regs) + scores + softmax ----
  float p[3][4];
  {
    float s[3][4];
    {
      float qb = 0.f;
      #pragma unroll
      for (int nt = 0; nt < 4; ++nt) qb = fmaf(qvv[nt], bk[nt * 16 + m16], qb);
      #pragma unroll
      for (int mt = 0; mt < 3; ++mt)
        #pragma unroll
        for (int r = 0; r < 4; ++r) s[mt][r] = qb;
    }
    #pragma unroll
    for (int nh = 0; nh < 2; ++nh) {
      f32x4 ka[3][2];
      #pragma unroll
      for (int mt = 0; mt < 3; ++mt) { ka[mt][0] = zero4(); ka[mt][1] = zero4(); }
      #pragma unroll
      for (int ks = 0; ks < 2; ++ks) {
        bf16x8 b0 = WkB[(ks * 4 + quad) * 64 + nh * 32 + m16];
        bf16x8 b1 = WkB[(ks * 4 + quad) * 64 + nh * 32 + 16 + m16];
        #pragma unroll
        for (int mt = 0; mt < 3; ++mt) {
          ka[mt][0] = __builtin_amdgcn_mfma_f32_16x16x32_bf16(a8[mt][ks], b0, ka[mt][0], 0, 0, 0);
          ka[mt][1] = __builtin_amdgcn_mfma_f32_16x16x32_bf16(a8[mt][ks], b1, ka[mt][1], 0, 0, 0);
        }
      }
      #pragma unroll
      for (int mt = 0; mt < 3; ++mt)
        #pragma unroll
        for (int r = 0; r < 4; ++r) {
          s[mt][r] = fmaf(qvv[nh * 2],     ka[mt][0][r], s[mt][r]);
          s[mt][r] = fmaf(qvv[nh * 2 + 1], ka[mt][1][r], s[mt][r]);
        }
    }
    // reduce over the 16 m16-lanes (c dimension)
    #pragma unroll
    for (int mt = 0; mt < 3; ++mt)
      #pragma unroll
      for (int r = 0; r < 4; ++r) {
        float t = s[mt][r];
        t += __shfl_xor(t, 1, 64);
        t += __shfl_xor(t, 2, 64);
        t += __shfl_xor(t, 4, 64);
        t += __shfl_xor(t, 8, 64);
        s[mt][r] = t;
      }
    // softmax over 48 t (12 local + cross-quad reduce)
    float mx = -INFINITY;
    #pragma unroll
    for (int mt = 0; mt < 3; ++mt)
      #pragma unroll
      for (int r = 0; r < 4; ++r) mx = fmaxf(mx, s[mt][r]);
    mx = fmaxf(mx, __shfl_xor(mx, 16, 64));
    mx = fmaxf(mx, __shfl_xor(mx, 32, 64));
    float l = 0.f;
    #pragma unroll
    for (int mt = 0; mt < 3; ++mt)
      #pragma unroll
      for (int r = 0; r < 4; ++r) {
        float e = __expf(s[mt][r] - mx);
        p[mt][r] = e;
        l += e;
      }
    l += __shfl_xor(l, 16, 64);
    l += __shfl_xor(l, 32, 64);
    float rl = 1.f / l;
    #pragma unroll
    for (int mt = 0; mt < 3; ++mt)
      #pragma unroll
      for (int r = 0; r < 4; ++r) p[mt][r] *= rl;
  }

  // ---- v pass (two halves) + ctx in registers (sum p = 1 folds bv) ----
  {
    float cx[4];
    #pragma unroll
    for (int nh = 0; nh < 2; ++nh) {
      f32x4 va[3][2];
      #pragma unroll
      for (int mt = 0; mt < 3; ++mt) { va[mt][0] = zero4(); va[mt][1] = zero4(); }
      #pragma unroll
      for (int ks = 0; ks < 2; ++ks) {
        bf16x8 b0 = WvB[(ks * 4 + quad) * 64 + nh * 32 + m16];
        bf16x8 b1 = WvB[(ks * 4 + quad) * 64 + nh * 32 + 16 + m16];
        #pragma unroll
        for (int mt = 0; mt < 3; ++mt) {
          va[mt][0] = __builtin_amdgcn_mfma_f32_16x16x32_bf16(a8[mt][ks], b0, va[mt][0], 0, 0, 0);
          va[mt][1] = __builtin_amdgcn_mfma_f32_16x16x32_bf16(a8[mt][ks], b1, va[mt][1], 0, 0, 0);
        }
      }
      #pragma unroll
      for (int j = 0; j < 2; ++j) {
        float a = 0.f;
        #pragma unroll
        for (int mt = 0; mt < 3; ++mt)
          #pragma unroll
          for (int r = 0; r < 4; ++r)
            a = fmaf(p[mt][r], va[mt][j][r], a);
        cx[nh * 2 + j] = a;
      }
    }
    #pragma unroll
    for (int nt = 0; nt < 4; ++nt) {
      cx[nt] += __shfl_xor(cx[nt], 16, 64);
      cx[nt] += __shfl_xor(cx[nt], 32, 64);
    }
    if (quad == 0) {
      #pragma unroll
      for (int nt = 0; nt < 4; ++nt)
        ctx[(size_t)seq * 64 + nt * 16 + m16] = cx[nt] + bv[nt * 16 + m16];
    }
  }
}

// ---------------------------------------------------------------------------
// MLP kernel (MFMA layers 1-2, fp32 layer 3): 16 rows/block, 2048 blocks
// (8/CU).  Xs padded stride 68; layer 3 uses 4 accumulators + float4 z2.
// ---------------------------------------------------------------------------
__global__ __launch_bounds__(256) void mlp_kernel(
    const float* __restrict__ ctx, const float* __restrict__ ws,
    const float* __restrict__ b1, const float* __restrict__ b2,
    const float* __restrict__ W3, const float* __restrict__ b3,
    float* __restrict__ out)
{
  __shared__ __bf16 Xs[16 * 68];    // 2176 B
  __shared__ __bf16 z1[16 * 264];   // 8448 B
  __shared__ float  z2[16 * 132];   // 8448 B

  const int tid  = threadIdx.x;
  const int r0   = blockIdx.x * 16;
  const int lane = tid & 63;
  const int wv   = tid >> 6;
  const int m16  = lane & 15;
  const int quad = lane >> 4;

  const __bf16* wsb = (const __bf16*)ws;
  const bf16x8* W1B = (const bf16x8*)(wsb + OFF_W1);
  const bf16x8* W2B = (const bf16x8*)(wsb + OFF_W2);

  // load 16 ctx rows (1024 floats = 256 float4), cast bf16 -> Xs
  {
    int row = tid >> 4, c4 = (tid & 15) * 4;
    float4 a = *(const float4*)(ctx + (size_t)(r0 + row) * 64 + c4);
    __bf16* d = &Xs[row * 68 + c4];
    d[0] = (__bf16)a.x; d[1] = (__bf16)a.y; d[2] = (__bf16)a.z; d[3] = (__bf16)a.w;
  }
  __syncthreads();

  // ---- layer 1: M=16 N=256 K=64; wave covers n in [wv*64, wv*64+64) ----
  {
    bf16x8 a8[2];
    #pragma unroll
    for (int ks = 0; ks < 2; ++ks)
      a8[ks] = *(const bf16x8*)&Xs[m16 * 68 + ks * 32 + quad * 8];
    f32x4 acc[4] = {zero4(), zero4(), zero4(), zero4()};
    #pragma unroll
    for (int nt = 0; nt < 4; ++nt) {
      int n = wv * 64 + nt * 16 + m16;
      #pragma unroll
      for (int ks = 0; ks < 2; ++ks)
        acc[nt] = __builtin_amdgcn_mfma_f32_16x16x32_bf16(
            a8[ks], W1B[(ks * 4 + quad) * 256 + n], acc[nt], 0, 0, 0);
    }
    #pragma unroll
    for (int nt = 0; nt < 4; ++nt) {
      int n = wv * 64 + nt * 16 + m16;
      float bb = b1[n];
      #pragma unroll
      for (int r = 0; r < 4; ++r)
        z1[(quad * 4 + r) * 264 + n] = (__bf16)fmaxf(acc[nt][r] + bb, 0.f);
    }
  }
  __syncthreads();

  // ---- layer 2: M=16 N=128 K=256; wave covers n in [wv*32, wv*32+32) ----
  {
    f32x4 acc[2] = {zero4(), zero4()};
    #pragma unroll 2
    for (int ks = 0; ks < 8; ++ks) {
      bf16x8 a = *(const bf16x8*)&z1[m16 * 264 + ks * 32 + quad * 8];
      #pragma unroll
      for (int nt = 0; nt < 2; ++nt)
        acc[nt] = __builtin_amdgcn_mfma_f32_16x16x32_bf16(
            a, W2B[(ks * 4 + quad) * 128 + wv * 32 + nt * 16 + m16], acc[nt], 0, 0, 0);
    }
    #pragma unroll
    for (int nt = 0; nt < 2; ++nt) {
      int n = wv * 32 + nt * 16 + m16;
      float bb = b2[n];
      #pragma unroll
      for (int r = 0; r < 4; ++r)
        z2[(quad * 4 + r) * 132 + n] = fmaxf(acc[nt][r] + bb, 0.f);
    }
  }
  __syncthreads();

  // ---- layer 3 (fp32, 16x12 K=128) + transposed store out[b][p][n] ----
  if (tid < 16 * NP) {
    int r = tid / NP, pp = tid - r * NP;
    const float* zr = z2 + r * 132;
    float a0 = b3[pp], a1 = 0.f, a2 = 0.f, a3 = 0.f;
    #pragma unroll 8
    for (int k = 0; k < 128; k += 4) {
      float4 f = *(const float4*)(zr + k);
      a0 = fmaf(f.x, W3[k * NP + pp],       a0);
      a1 = fmaf(f.y, W3[(k + 1) * NP + pp], a1);
      a2 = fmaf(f.z, W3[(k + 2) * NP + pp], a2);
      a3 = fmaf(f.w, W3[(k + 3) * NP + pp], a3);
    }
    float a = (a0 + a1) + (a2 + a3);
    int row = r0 + r;
    int bb = row >> 11, nn = row & 2047;
    out[(size_t)bb * (NP * 2048) + pp * 2048 + nn] = a;
  }
}

// ---------------------------------------------------------------------------
extern "C" void kernel_launch(void* const* d_in, const int* in_sizes, int n_in,
                              void* d_out, int out_size, void* d_ws, size_t ws_size,
                              hipStream_t stream) {
  const float* x      = (const float*)d_in[0];
  const float* W_in   = (const float*)d_in[1];
  const float* b_in   = (const float*)d_in[2];
  const float* W_conv = (const float*)d_in[3];
  const float* b_conv = (const float*)d_in[4];
  const float* Wq     = (const float*)d_in[5];
  const float* bq     = (const float*)d_in[6];
  const float* Wk     = (const float*)d_in[7];
  const float* bk     = (const float*)d_in[8];
  const float* Wv     = (const float*)d_in[9];
  const float* bv     = (const float*)d_in[10];
  const float* W1     = (const float*)d_in[11];
  const float* b1     = (const float*)d_in[12];
  const float* W2     = (const float*)d_in[13];
  const float* b2     = (const float*)d_in[14];
  const float* W3     = (const float*)d_in[15];
  const float* b3     = (const float*)d_in[16];
  float* ws  = (float*)d_ws;
  float* out = (float*)d_out;

  prep_kernel<<<265, 256, 0, stream>>>(W_in, b_in, W_conv, b_conv, Wk, Wv, Wq, W1, W2, ws);
  attn_kernel<<<NSEQ / 2, 128, 0, stream>>>(x, bq, bk, bv, ws, ws + WS_CTX);
  mlp_kernel<<<NSEQ / 16, 256, 0, stream>>>(ws + WS_CTX, ws, b1, b2, W3, b3, out);
}

// Round 6
// 378.072 us; speedup vs baseline: 3.7504x; 1.0289x over previous
//
#include <hip/hip_runtime.h>
#include <hip/hip_bf16.h>
#include <math.h>

// Problem constants
#define TT 48
#define NSEQ (16*2048)
#define NP 12

// MFMA fragment types (gfx950: mfma_f32_16x16x32_bf16)
typedef __bf16 bf16x8 __attribute__((ext_vector_type(8)));
typedef float  f32x4  __attribute__((ext_vector_type(4)));

// ws layout.
// bf16 region (ws viewed as __bf16*), all B-frag swizzled [((k>>3)*N + n)*8 + (k&7)]:
//   [0)      WccB  96x64   (folded W_in @ W_conv)
//   [6144)   MqkB  64x64   (0.125 * Wq @ Wk^T, k-index = d, n-index = c)
//   [10240)  WvB   64x64
//   [18432)  W1B   64x256
//   [34816)  W2B   256x128   -> ends 67584 bf16 == float idx 33792
// float region (ws viewed as float*):
//   [33792)  btot 64   (bc0+bc1+bc2+b_conv)
//   [33856)  bc0  64
//   [33920)  bc2  64
//   [33984)  kv0  64   (0.125 * Wk @ bq)
//   [34048)  ctx  32768*64
#define OFF_WCC 0
#define OFF_MQK 6144
#define OFF_WV  10240
#define OFF_W1  18432
#define OFF_W2  34816
#define WS_BTOT 33792
#define WS_BC0  33856
#define WS_BC2  33920
#define WS_KV0  33984
#define WS_CTX  34048

__device__ __forceinline__ f32x4 zero4() {
  f32x4 z; z[0] = 0.f; z[1] = 0.f; z[2] = 0.f; z[3] = 0.f; return z;
}

union PackU { bf16x8 v; __hip_bfloat162 h[4]; };

// packed fp32x8 -> bf16x8 conversion (v_cvt_pk_bf16_f32)
__device__ __forceinline__ bf16x8 pack8(float4 a, float4 b) {
  PackU u;
  u.h[0] = __float22bfloat162_rn(make_float2(a.x, a.y));
  u.h[1] = __float22bfloat162_rn(make_float2(a.z, a.w));
  u.h[2] = __float22bfloat162_rn(make_float2(b.x, b.y));
  u.h[3] = __float22bfloat162_rn(make_float2(b.z, b.w));
  return u.v;
}

// ---------------------------------------------------------------------------
// Prep: fold W_in into conv weights; precompute M_qk = 0.125*Wq@Wk^T and
// kv0 = 0.125*Wk@bq (softmax shift-invariance kills all other q/k terms);
// convert all GEMM weights to bf16 in B-frag-swizzled order.
// ---------------------------------------------------------------------------
__global__ __launch_bounds__(256) void prep_kernel(
    const float* __restrict__ W_in, const float* __restrict__ b_in,
    const float* __restrict__ W_conv, const float* __restrict__ b_conv,
    const float* __restrict__ Wk, const float* __restrict__ Wv,
    const float* __restrict__ Wq, const float* __restrict__ bq,
    const float* __restrict__ W1, const float* __restrict__ W2,
    float* __restrict__ ws)
{
  __bf16* wsb = (__bf16*)ws;
  const int tid = threadIdx.x;
  const int bid = blockIdx.x;
  if (bid < 24) {                       // WccB: fold W_in into W_conv
    int gid = bid * 256 + tid;          // 0..6143
    int kk = gid >> 6;                  // 0..95
    int c  = gid & 63;
    int dt = kk >> 5;
    int e  = kk & 31;
    const float* wrow = W_in + e * 64;
    const float* wc   = W_conv + dt * 4096 + c;
    float acc = 0.f;
    #pragma unroll 8
    for (int c0 = 0; c0 < 64; ++c0)
      acc = fmaf(wrow[c0], wc[c0 * 64], acc);
    wsb[OFF_WCC + ((kk >> 3) * 64 + c) * 8 + (kk & 7)] = (__bf16)acc;
  } else if (bid < 40) {                // MqkB = 0.125 * Wq @ Wk^T  (k=d, n=c)
    int gid = (bid - 24) * 256 + tid;   // 0..4095
    int d = gid >> 6, c = gid & 63;
    const float* qr = Wq + d * 64;
    const float* kr = Wk + c * 64;
    float acc = 0.f;
    #pragma unroll 8
    for (int j = 0; j < 64; ++j) acc = fmaf(qr[j], kr[j], acc);
    wsb[OFF_MQK + ((d >> 3) * 64 + c) * 8 + (d & 7)] = (__bf16)(0.125f * acc);
  } else if (bid < 56) {                // WvB
    int gid = (bid - 40) * 256 + tid;
    int kk = gid >> 6, c = gid & 63;
    wsb[OFF_WV + ((kk >> 3) * 64 + c) * 8 + (kk & 7)] = (__bf16)Wv[kk * 64 + c];
  } else if (bid < 120) {               // W1B (64x256)
    int gid = (bid - 56) * 256 + tid;   // 0..16383
    int kk = gid >> 8, n = gid & 255;
    wsb[OFF_W1 + ((kk >> 3) * 256 + n) * 8 + (kk & 7)] = (__bf16)W1[kk * 256 + n];
  } else if (bid < 248) {               // W2B (256x128)
    int gid = (bid - 120) * 256 + tid;  // 0..32767
    int kk = gid >> 7, n = gid & 127;
    wsb[OFF_W2 + ((kk >> 3) * 128 + n) * 8 + (kk & 7)] = (__bf16)W2[kk * 128 + n];
  } else if (tid < 64) {                // biases + kv0
    int c = tid;
    float s[3];
    for (int dt = 0; dt < 3; ++dt) {
      const float* wc = W_conv + dt * 4096 + c;
      float a = 0.f;
      for (int c0 = 0; c0 < 64; ++c0) a = fmaf(b_in[c0], wc[c0 * 64], a);
      s[dt] = a;
    }
    ws[WS_BC0 + c]  = s[0];
    ws[WS_BC2 + c]  = s[2];
    ws[WS_BTOT + c] = s[0] + s[1] + s[2] + b_conv[c];
    float a = 0.f;
    const float* kr = Wk + c * 64;
    for (int j = 0; j < 64; ++j) a = fmaf(kr[j], bq[j], a);
    ws[WS_KV0 + c] = 0.125f * a;
  }
}

// ---------------------------------------------------------------------------
// Attention kernel: ONE WAVE = ONE SEQUENCE, block = 128 threads (2 seqs).
// No __syncthreads.  Algebraically reduced attention:
//   scores[t] = h1[t] . w,  w = MqkB-GEMV(h1[47]) + kv0   (k/q passes gone)
//   scores-GEMV uses broadcast-w B-frags -> scores replicated across all 16
//   C columns -> softmax needs only 4 cross-quad shuffles (was 48+).
//   ctx = sum_t p[t] * V[t] + bv (v-pass MFMA, per-lane weighting).
// LDS 12.9 KB/block; launch_bounds(128,5) -> ~20 waves/CU.
// ---------------------------------------------------------------------------
__global__ __launch_bounds__(128, 5) void attn_kernel(
    const float* __restrict__ x, const float* __restrict__ bv,
    const float* __restrict__ ws, float* __restrict__ ctx)
{
  __shared__ __bf16 h1s[2][48 * 66];   // 12672 B
  __shared__ __bf16 wbufs[2][64];      // 256 B

  const int tid  = threadIdx.x;
  const int lane = tid & 63;
  const int wv   = tid >> 6;
  const int m16  = lane & 15;
  const int quad = lane >> 4;
  const int seq  = blockIdx.x * 2 + wv;
  __bf16* h1   = h1s[wv];
  __bf16* wbuf = wbufs[wv];

  const __bf16* wsb  = (const __bf16*)ws;
  const bf16x8* WccB = (const bf16x8*)(wsb + OFF_WCC);
  const bf16x8* MqkB = (const bf16x8*)(wsb + OFF_MQK);
  const bf16x8* WvB  = (const bf16x8*)(wsb + OFF_WV);
  const float*  wsf  = ws;
  const float*  xseq = x + (size_t)seq * (TT * 32);

  // ---- build all 9 x A-frags once (18 float4 loads, packed cvts) ----
  bf16x8 af[3][3];   // [mt][ks]
  #pragma unroll
  for (int mt = 0; mt < 3; ++mt)
    #pragma unroll
    for (int ks = 0; ks < 3; ++ks) {
      const int tg = mt * 16 + m16 + ks - 1;
      const bool need_guard = (mt == 0 && ks == 0) || (mt == 2 && ks == 2);
      if (!need_guard || (tg >= 0 && tg < 48)) {
        const float* ap = xseq + tg * 32 + quad * 8;
        af[mt][ks] = pack8(*(const float4*)ap, *(const float4*)(ap + 4));
      } else {
        #pragma unroll
        for (int j = 0; j < 8; ++j) af[mt][ks][j] = (__bf16)0.f;
      }
    }

  // ---- conv GEMM in two 32-channel halves (24 acc regs live) ----
  #pragma unroll
  for (int nh = 0; nh < 2; ++nh) {
    f32x4 acc[3][2];
    #pragma unroll
    for (int mt = 0; mt < 3; ++mt) { acc[mt][0] = zero4(); acc[mt][1] = zero4(); }
    #pragma unroll
    for (int ks = 0; ks < 3; ++ks) {
      bf16x8 b0 = WccB[(ks * 4 + quad) * 64 + nh * 32 + m16];
      bf16x8 b1 = WccB[(ks * 4 + quad) * 64 + nh * 32 + 16 + m16];
      #pragma unroll
      for (int mt = 0; mt < 3; ++mt) {
        acc[mt][0] = __builtin_amdgcn_mfma_f32_16x16x32_bf16(af[mt][ks], b0, acc[mt][0], 0, 0, 0);
        acc[mt][1] = __builtin_amdgcn_mfma_f32_16x16x32_bf16(af[mt][ks], b1, acc[mt][1], 0, 0, 0);
      }
    }
    // epilogue: bias (+pad-row fix), relu, bf16 -> LDS (stride 66)
    #pragma unroll
    for (int j = 0; j < 2; ++j) {
      const int c = nh * 32 + j * 16 + m16;
      const float bt  = wsf[WS_BTOT + c];
      const float b0v = wsf[WS_BC0 + c];
      const float b2v = wsf[WS_BC2 + c];
      #pragma unroll
      for (int mt = 0; mt < 3; ++mt)
        #pragma unroll
        for (int r = 0; r < 4; ++r) {
          const int trow = mt * 16 + quad * 4 + r;
          float v = acc[mt][j][r] + bt;
          if (mt == 0 && r == 0 && quad == 0) v -= b0v;   // t==0
          if (mt == 2 && r == 3 && quad == 3) v -= b2v;   // t==47
          h1[trow * 66 + c] = (__bf16)fmaxf(v, 0.f);
        }
    }
  }
  // within-wave LDS write->read fence (no barrier: one wave owns its seq)
  __asm__ __volatile__("s_waitcnt lgkmcnt(0)" ::: "memory");

  // ---- A-fragments of h1 (shared by w-GEMV, scores, v) ----
  bf16x8 a8[3][2];
  #pragma unroll
  for (int mt = 0; mt < 3; ++mt)
    #pragma unroll
    for (int ks = 0; ks < 2; ++ks)
      a8[mt][ks] = *(const bf16x8*)&h1[(mt * 16 + m16) * 66 + ks * 32 + quad * 8];

  // ---- w-GEMV: w = 0.125*(Wq Wk^T)^T h1_47 + kv0, via rows-32..47 tile ----
  {
    f32x4 qa[4] = {zero4(), zero4(), zero4(), zero4()};
    #pragma unroll
    for (int ks = 0; ks < 2; ++ks)
      #pragma unroll
      for (int nt = 0; nt < 4; ++nt)
        qa[nt] = __builtin_amdgcn_mfma_f32_16x16x32_bf16(
            a8[2][ks], MqkB[(ks * 4 + quad) * 64 + nt * 16 + m16], qa[nt], 0, 0, 0);
    if (quad == 3) {   // row 47 = quad 3, reg 3; lane holds w[nt*16+m16]
      #pragma unroll
      for (int nt = 0; nt < 4; ++nt)
        wbuf[nt * 16 + m16] = (__bf16)(qa[nt][3] + wsf[WS_KV0 + nt * 16 + m16]);
    }
  }
  __asm__ __volatile__("s_waitcnt lgkmcnt(0)" ::: "memory");

  // ---- scores-GEMV with broadcast-w B-frags: C[t][n] = scores[t] for all n ----
  float p[3][4];
  {
    bf16x8 wB0 = *(const bf16x8*)&wbuf[quad * 8];
    bf16x8 wB1 = *(const bf16x8*)&wbuf[32 + quad * 8];
    f32x4 sa[3] = {zero4(), zero4(), zero4()};
    #pragma unroll
    for (int mt = 0; mt < 3; ++mt) {
      sa[mt] = __builtin_amdgcn_mfma_f32_16x16x32_bf16(a8[mt][0], wB0, sa[mt], 0, 0, 0);
      sa[mt] = __builtin_amdgcn_mfma_f32_16x16x32_bf16(a8[mt][1], wB1, sa[mt], 0, 0, 0);
    }
    // softmax over 48 t: 12 logits/lane (replicated across m16), cross-quad only
    float mx = -INFINITY;
    #pragma unroll
    for (int mt = 0; mt < 3; ++mt)
      #pragma unroll
      for (int r = 0; r < 4; ++r) mx = fmaxf(mx, sa[mt][r]);
    mx = fmaxf(mx, __shfl_xor(mx, 16, 64));
    mx = fmaxf(mx, __shfl_xor(mx, 32, 64));
    float l = 0.f;
    #pragma unroll
    for (int mt = 0; mt < 3; ++mt)
      #pragma unroll
      for (int r = 0; r < 4; ++r) {
        float e = __expf(sa[mt][r] - mx);
        p[mt][r] = e;
        l += e;
      }
    l += __shfl_xor(l, 16, 64);
    l += __shfl_xor(l, 32, 64);
    float rl = 1.f / l;
    #pragma unroll
    for (int mt = 0; mt < 3; ++mt)
      #pragma unroll
      for (int r = 0; r < 4; ++r) p[mt][r] *= rl;
  }

  // ---- v pass (two halves) + ctx in registers (sum p = 1 folds bv) ----
  {
    float cx[4];
    #pragma unroll
    for (int nh = 0; nh < 2; ++nh) {
      f32x4 va[3][2];
      #pragma unroll
      for (int mt = 0; mt < 3; ++mt) { va[mt][0] = zero4(); va[mt][1] = zero4(); }
      #pragma unroll
      for (int ks = 0; ks < 2; ++ks) {
        bf16x8 b0 = WvB[(ks * 4 + quad) * 64 + nh * 32 + m16];
        bf16x8 b1 = WvB[(ks * 4 + quad) * 64 + nh * 32 + 16 + m16];
        #pragma unroll
        for (int mt = 0; mt < 3; ++mt) {
          va[mt][0] = __builtin_amdgcn_mfma_f32_16x16x32_bf16(a8[mt][ks], b0, va[mt][0], 0, 0, 0);
          va[mt][1] = __builtin_amdgcn_mfma_f32_16x16x32_bf16(a8[mt][ks], b1, va[mt][1], 0, 0, 0);
        }
      }
      #pragma unroll
      for (int j = 0; j < 2; ++j) {
        float a = 0.f;
        #pragma unroll
        for (int mt = 0; mt < 3; ++mt)
          #pragma unroll
          for (int r = 0; r < 4; ++r)
            a = fmaf(p[mt][r], va[mt][j][r], a);
        cx[nh * 2 + j] = a;
      }
    }
    #pragma unroll
    for (int nt = 0; nt < 4; ++nt) {
      cx[nt] += __shfl_xor(cx[nt], 16, 64);
      cx[nt] += __shfl_xor(cx[nt], 32, 64);
    }
    if (quad == 0) {
      #pragma unroll
      for (int nt = 0; nt < 4; ++nt)
        ctx[(size_t)seq * 64 + nt * 16 + m16] = cx[nt] + bv[nt * 16 + m16];
    }
  }
}

// ---------------------------------------------------------------------------
// MLP kernel (MFMA layers 1-2, fp32 layer 3): 16 rows/block, 2048 blocks
// (8/CU).  Xs padded stride 68; layer 3 uses 4 accumulators + float4 z2.
// ---------------------------------------------------------------------------
__global__ __launch_bounds__(256) void mlp_kernel(
    const float* __restrict__ ctx, const float* __restrict__ ws,
    const float* __restrict__ b1, const float* __restrict__ b2,
    const float* __restrict__ W3, const float* __restrict__ b3,
    float* __restrict__ out)
{
  __shared__ __bf16 Xs[16 * 68];    // 2176 B
  __shared__ __bf16 z1[16 * 264];   // 8448 B
  __shared__ float  z2[16 * 132];   // 8448 B

  const int tid  = threadIdx.x;
  const int r0   = blockIdx.x * 16;
  const int lane = tid & 63;
  const int wv   = tid >> 6;
  const int m16  = lane & 15;
  const int quad = lane >> 4;

  const __bf16* wsb = (const __bf16*)ws;
  const bf16x8* W1B = (const bf16x8*)(wsb + OFF_W1);
  const bf16x8* W2B = (const bf16x8*)(wsb + OFF_W2);

  // load 16 ctx rows (1024 floats = 256 float4), cast bf16 -> Xs
  {
    int row = tid >> 4, c4 = (tid & 15) * 4;
    float4 a = *(const float4*)(ctx + (size_t)(r0 + row) * 64 + c4);
    __bf16* d = &Xs[row * 68 + c4];
    d[0] = (__bf16)a.x; d[1] = (__bf16)a.y; d[2] = (__bf16)a.z; d[3] = (__bf16)a.w;
  }
  __syncthreads();

  // ---- layer 1: M=16 N=256 K=64; wave covers n in [wv*64, wv*64+64) ----
  {
    bf16x8 a8[2];
    #pragma unroll
    for (int ks = 0; ks < 2; ++ks)
      a8[ks] = *(const bf16x8*)&Xs[m16 * 68 + ks * 32 + quad * 8];
    f32x4 acc[4] = {zero4(), zero4(), zero4(), zero4()};
    #pragma unroll
    for (int nt = 0; nt < 4; ++nt) {
      int n = wv * 64 + nt * 16 + m16;
      #pragma unroll
      for (int ks = 0; ks < 2; ++ks)
        acc[nt] = __builtin_amdgcn_mfma_f32_16x16x32_bf16(
            a8[ks], W1B[(ks * 4 + quad) * 256 + n], acc[nt], 0, 0, 0);
    }
    #pragma unroll
    for (int nt = 0; nt < 4; ++nt) {
      int n = wv * 64 + nt * 16 + m16;
      float bb = b1[n];
      #pragma unroll
      for (int r = 0; r < 4; ++r)
        z1[(quad * 4 + r) * 264 + n] = (__bf16)fmaxf(acc[nt][r] + bb, 0.f);
    }
  }
  __syncthreads();

  // ---- layer 2: M=16 N=128 K=256; wave covers n in [wv*32, wv*32+32) ----
  {
    f32x4 acc[2] = {zero4(), zero4()};
    #pragma unroll 2
    for (int ks = 0; ks < 8; ++ks) {
      bf16x8 a = *(const bf16x8*)&z1[m16 * 264 + ks * 32 + quad * 8];
      #pragma unroll
      for (int nt = 0; nt < 2; ++nt)
        acc[nt] = __builtin_amdgcn_mfma_f32_16x16x32_bf16(
            a, W2B[(ks * 4 + quad) * 128 + wv * 32 + nt * 16 + m16], acc[nt], 0, 0, 0);
    }
    #pragma unroll
    for (int nt = 0; nt < 2; ++nt) {
      int n = wv * 32 + nt * 16 + m16;
      float bb = b2[n];
      #pragma unroll
      for (int r = 0; r < 4; ++r)
        z2[(quad * 4 + r) * 132 + n] = fmaxf(acc[nt][r] + bb, 0.f);
    }
  }
  __syncthreads();

  // ---- layer 3 (fp32, 16x12 K=128) + transposed store out[b][p][n] ----
  if (tid < 16 * NP) {
    int r = tid / NP, pp = tid - r * NP;
    const float* zr = z2 + r * 132;
    float a0 = b3[pp], a1 = 0.f, a2 = 0.f, a3 = 0.f;
    #pragma unroll 8
    for (int k = 0; k < 128; k += 4) {
      float4 f = *(const float4*)(zr + k);
      a0 = fmaf(f.x, W3[k * NP + pp],       a0);
      a1 = fmaf(f.y, W3[(k + 1) * NP + pp], a1);
      a2 = fmaf(f.z, W3[(k + 2) * NP + pp], a2);
      a3 = fmaf(f.w, W3[(k + 3) * NP + pp], a3);
    }
    float a = (a0 + a1) + (a2 + a3);
    int row = r0 + r;
    int bb = row >> 11, nn = row & 2047;
    out[(size_t)bb * (NP * 2048) + pp * 2048 + nn] = a;
  }
}

// ---------------------------------------------------------------------------
extern "C" void kernel_launch(void* const* d_in, const int* in_sizes, int n_in,
                              void* d_out, int out_size, void* d_ws, size_t ws_size,
                              hipStream_t stream) {
  const float* x      = (const float*)d_in[0];
  const float* W_in   = (const float*)d_in[1];
  const float* b_in   = (const float*)d_in[2];
  const float* W_conv = (const float*)d_in[3];
  const float* b_conv = (const float*)d_in[4];
  const float* Wq     = (const float*)d_in[5];
  const float* bq     = (const float*)d_in[6];
  const float* Wk     = (const float*)d_in[7];
  const float* bk     = (const float*)d_in[8];  (void)bk;
  const float* Wv     = (const float*)d_in[9];
  const float* bv     = (const float*)d_in[10];
  const float* W1     = (const float*)d_in[11];
  const float* b1     = (const float*)d_in[12];
  const float* W2     = (const float*)d_in[13];
  const float* b2     = (const float*)d_in[14];
  const float* W3     = (const float*)d_in[15];
  const float* b3     = (const float*)d_in[16];
  float* ws  = (float*)d_ws;
  float* out = (float*)d_out;

  prep_kernel<<<249, 256, 0, stream>>>(W_in, b_in, W_conv, b_conv, Wk, Wv, Wq, bq, W1, W2, ws);
  attn_kernel<<<NSEQ / 2, 128, 0, stream>>>(x, bv, ws, ws + WS_CTX);
  mlp_kernel<<<NSEQ / 16, 256, 0, stream>>>(ws + WS_CTX, ws, b1, b2, W3, b3, out);
}